// Round 2
// baseline (1636.646 us; speedup 1.0000x reference)
//
#include <hip/hip_runtime.h>
#include <cstdint>
#include <cstddef>

// DecoderBlock on MI355X (gfx950), round 1: baseline (compile fix of r0).
// Linear layers: bf16 hi/lo split MFMA (3 passes -> ~fp32 accuracy).
// Attention: flash-style, bf16 MFMA core, fp32 online softmax.
// Workspace: [64 MiB transposed bf16 weights][7 x 16 MiB fp32 buffers] = 176 MiB.

typedef __bf16 bf16;
typedef __attribute__((ext_vector_type(4))) float f32x4;
typedef __attribute__((ext_vector_type(8))) __bf16 bf16x8;
typedef __attribute__((ext_vector_type(4))) __bf16 bf16x4;

#define MFMA(a, b, c) __builtin_amdgcn_mfma_f32_16x16x32_bf16((a), (b), (c), 0, 0, 0)

constexpr int D_MODEL = 1024;
constexpr int NHEAD   = 16;
constexpr int D_K     = 64;
constexpr int S_LEN   = 2048;
constexpr int BATCH   = 2;
constexpr int M_ROWS  = S_LEN * BATCH;  // 4096

struct bfp { bf16 h, l; };
__device__ __forceinline__ bfp fsplit(float f) {
  bfp r;
  r.h = (bf16)f;
  r.l = (bf16)(f - (float)r.h);
  return r;
}

// ---------------------------------------------------------------------------
// Weight cast + transpose: W[K][N] fp32 -> Th[N][K], Tl[N][K] bf16 hi/lo
// ---------------------------------------------------------------------------
__global__ void wcast_t(const float* __restrict__ W, bf16* __restrict__ Th,
                        bf16* __restrict__ Tl, int K, int N) {
  __shared__ float t[32][33];
  const int kt = blockIdx.x * 32, nt = blockIdx.y * 32;
  const int tx = threadIdx.x, ty = threadIdx.y;  // 32 x 8
#pragma unroll
  for (int i = 0; i < 4; ++i)
    t[ty * 4 + i][tx] = W[(size_t)(kt + ty * 4 + i) * N + nt + tx];
  __syncthreads();
#pragma unroll
  for (int i = 0; i < 4; ++i) {
    int n = nt + ty * 4 + i;
    bfp s = fsplit(t[tx][ty * 4 + i]);
    Th[(size_t)n * K + kt + tx] = s.h;
    Tl[(size_t)n * K + kt + tx] = s.l;
  }
}

// ---------------------------------------------------------------------------
// Split-precision GEMM: C[M][N] = A[M][K](fp32) * W + bias, W pre-transposed
// as Wh/Wl [N][ldw] bf16. flags: bit0 relu, bit1 accumulate (skip bias).
// ---------------------------------------------------------------------------
__launch_bounds__(256)
__global__ void gemm_split(const float* __restrict__ A,
                           const bf16* __restrict__ Wh,
                           const bf16* __restrict__ Wl,
                           const float* __restrict__ bias,
                           float* __restrict__ C,
                           int M, int N, int K, int ldw, int flags) {
  __shared__ bf16 Ah[128][40];
  __shared__ bf16 Al[128][40];
  __shared__ bf16 Bh[128][40];
  __shared__ bf16 Bl[128][40];
  const int tid  = threadIdx.x;
  const int lane = tid & 63, wid = tid >> 6;
  const int wr = wid >> 1, wc = wid & 1;
  const int g = lane >> 4, lr = lane & 15;
  const int m0 = blockIdx.y * 128, n0 = blockIdx.x * 128;
  const int srow = tid >> 3, sc4 = (tid & 7) * 4;

  f32x4 acc[4][4] = {};

  for (int k0 = 0; k0 < K; k0 += 32) {
    __syncthreads();
#pragma unroll
    for (int p = 0; p < 4; ++p) {
      int r = p * 32 + srow;
      float4 v = *reinterpret_cast<const float4*>(&A[(size_t)(m0 + r) * K + k0 + sc4]);
      bf16x4 h, l;
      bfp s0 = fsplit(v.x); h[0] = s0.h; l[0] = s0.l;
      bfp s1 = fsplit(v.y); h[1] = s1.h; l[1] = s1.l;
      bfp s2 = fsplit(v.z); h[2] = s2.h; l[2] = s2.l;
      bfp s3 = fsplit(v.w); h[3] = s3.h; l[3] = s3.l;
      *reinterpret_cast<bf16x4*>(&Ah[r][sc4]) = h;
      *reinterpret_cast<bf16x4*>(&Al[r][sc4]) = l;
    }
#pragma unroll
    for (int p = 0; p < 4; ++p) {
      int r = p * 32 + srow;
      bf16x4 h = *reinterpret_cast<const bf16x4*>(&Wh[(size_t)(n0 + r) * ldw + k0 + sc4]);
      bf16x4 l = *reinterpret_cast<const bf16x4*>(&Wl[(size_t)(n0 + r) * ldw + k0 + sc4]);
      *reinterpret_cast<bf16x4*>(&Bh[r][sc4]) = h;
      *reinterpret_cast<bf16x4*>(&Bl[r][sc4]) = l;
    }
    __syncthreads();

    bf16x8 ah[4], al[4], bh[4], bl[4];
#pragma unroll
    for (int mi = 0; mi < 4; ++mi) {
      int r = wr * 64 + mi * 16 + lr;
      ah[mi] = *reinterpret_cast<const bf16x8*>(&Ah[r][g * 8]);
      al[mi] = *reinterpret_cast<const bf16x8*>(&Al[r][g * 8]);
    }
#pragma unroll
    for (int ni = 0; ni < 4; ++ni) {
      int r = wc * 64 + ni * 16 + lr;
      bh[ni] = *reinterpret_cast<const bf16x8*>(&Bh[r][g * 8]);
      bl[ni] = *reinterpret_cast<const bf16x8*>(&Bl[r][g * 8]);
    }
#pragma unroll
    for (int mi = 0; mi < 4; ++mi)
#pragma unroll
      for (int ni = 0; ni < 4; ++ni) {
        acc[mi][ni] = MFMA(ah[mi], bh[ni], acc[mi][ni]);
        acc[mi][ni] = MFMA(ah[mi], bl[ni], acc[mi][ni]);
        acc[mi][ni] = MFMA(al[mi], bh[ni], acc[mi][ni]);
      }
  }

#pragma unroll
  for (int mi = 0; mi < 4; ++mi)
#pragma unroll
    for (int ni = 0; ni < 4; ++ni) {
      int col = n0 + wc * 64 + ni * 16 + lr;
      float bv = (flags & 2) ? 0.f : bias[col];
#pragma unroll
      for (int r = 0; r < 4; ++r) {
        int row = m0 + wr * 64 + mi * 16 + g * 4 + r;
        float v = acc[mi][ni][r] + bv;
        if (flags & 1) v = fmaxf(v, 0.f);
        float* cp = &C[(size_t)row * N + col];
        if (flags & 2) v += *cp;
        *cp = v;
      }
    }
}

// ---------------------------------------------------------------------------
// Flash attention. Q,K,V,O fp32 [row = s*BATCH + b][col = h*64 + d].
// Grid: (S/64, BATCH*NHEAD). 4 waves/block, 16 q-rows/wave, KVBLK=32.
// ---------------------------------------------------------------------------
__launch_bounds__(256)
__global__ void attn_kernel(const float* __restrict__ Qg, const float* __restrict__ Kg,
                            const float* __restrict__ Vg, float* __restrict__ Og,
                            int causal) {
  __shared__ bf16 Kl[32][72];
  __shared__ bf16 Vt[64][40];
  __shared__ bf16 Pl[4][16][40];
  const int tid = threadIdx.x, lane = tid & 63, w = tid >> 6;
  const int g = lane >> 4, lr = lane & 15;
  const int qt = blockIdx.x, bh = blockIdx.y;
  const int b = bh >> 4, h = bh & 15;
  const int q0 = qt * 64 + w * 16;

  bf16x8 aq[2];
  {
    const float* qp = &Qg[((size_t)(q0 + lr) * BATCH + b) * D_MODEL + h * D_K];
#pragma unroll
    for (int kk = 0; kk < 2; ++kk) {
      float4 f0 = *reinterpret_cast<const float4*>(qp + kk * 32 + g * 8);
      float4 f1 = *reinterpret_cast<const float4*>(qp + kk * 32 + g * 8 + 4);
      bf16x8 a;
      a[0] = (bf16)(f0.x * 0.125f); a[1] = (bf16)(f0.y * 0.125f);
      a[2] = (bf16)(f0.z * 0.125f); a[3] = (bf16)(f0.w * 0.125f);
      a[4] = (bf16)(f1.x * 0.125f); a[5] = (bf16)(f1.y * 0.125f);
      a[6] = (bf16)(f1.z * 0.125f); a[7] = (bf16)(f1.w * 0.125f);
      aq[kk] = a;
    }
  }

  f32x4 acco[4] = {};
  float mrun[4], lrun[4];
#pragma unroll
  for (int r = 0; r < 4; ++r) { mrun[r] = -1e30f; lrun[r] = 0.f; }

  const int nkv = causal ? (qt * 2 + 2) : (S_LEN / 32);
  const int skey = tid >> 3, sd8 = (tid & 7) * 8;

  for (int kv = 0; kv < nkv; ++kv) {
    const int kv0 = kv * 32;
    __syncthreads();
    {
      const size_t rbase = ((size_t)(kv0 + skey) * BATCH + b) * D_MODEL + h * D_K + sd8;
      float4 f0 = *reinterpret_cast<const float4*>(&Kg[rbase]);
      float4 f1 = *reinterpret_cast<const float4*>(&Kg[rbase + 4]);
      bf16x4 h0, h1;
      h0[0] = (bf16)f0.x; h0[1] = (bf16)f0.y; h0[2] = (bf16)f0.z; h0[3] = (bf16)f0.w;
      h1[0] = (bf16)f1.x; h1[1] = (bf16)f1.y; h1[2] = (bf16)f1.z; h1[3] = (bf16)f1.w;
      *reinterpret_cast<bf16x4*>(&Kl[skey][sd8])     = h0;
      *reinterpret_cast<bf16x4*>(&Kl[skey][sd8 + 4]) = h1;
      float4 v0 = *reinterpret_cast<const float4*>(&Vg[rbase]);
      float4 v1 = *reinterpret_cast<const float4*>(&Vg[rbase + 4]);
      Vt[sd8 + 0][skey] = (bf16)v0.x; Vt[sd8 + 1][skey] = (bf16)v0.y;
      Vt[sd8 + 2][skey] = (bf16)v0.z; Vt[sd8 + 3][skey] = (bf16)v0.w;
      Vt[sd8 + 4][skey] = (bf16)v1.x; Vt[sd8 + 5][skey] = (bf16)v1.y;
      Vt[sd8 + 6][skey] = (bf16)v1.z; Vt[sd8 + 7][skey] = (bf16)v1.w;
    }
    __syncthreads();
    if (causal && kv0 > q0 + 15) continue;

    f32x4 s[2];
#pragma unroll
    for (int c = 0; c < 2; ++c) {
      f32x4 a = {};
#pragma unroll
      for (int kk = 0; kk < 2; ++kk) {
        bf16x8 bk = *reinterpret_cast<const bf16x8*>(&Kl[c * 16 + lr][kk * 32 + g * 8]);
        a = MFMA(aq[kk], bk, a);
      }
      s[c] = a;
    }
    if (causal) {
#pragma unroll
      for (int c = 0; c < 2; ++c) {
        int key = kv0 + c * 16 + lr;
#pragma unroll
        for (int r = 0; r < 4; ++r)
          if (key > q0 + g * 4 + r) s[c][r] = -1e30f;
      }
    }

    float p[2][4];
#pragma unroll
    for (int r = 0; r < 4; ++r) {
      float mx = fmaxf(s[0][r], s[1][r]);
#pragma unroll
      for (int off = 8; off >= 1; off >>= 1) mx = fmaxf(mx, __shfl_xor(mx, off));
      float mnew = fmaxf(mrun[r], mx);
      float sf = __expf(mrun[r] - mnew);
      float p0 = __expf(s[0][r] - mnew);
      float p1 = __expf(s[1][r] - mnew);
      float ps = p0 + p1;
#pragma unroll
      for (int off = 8; off >= 1; off >>= 1) ps += __shfl_xor(ps, off);
      lrun[r] = lrun[r] * sf + ps;
      mrun[r] = mnew;
#pragma unroll
      for (int t = 0; t < 4; ++t) acco[t][r] *= sf;
      p[0][r] = p0;
      p[1][r] = p1;
    }

#pragma unroll
    for (int c = 0; c < 2; ++c)
#pragma unroll
      for (int r = 0; r < 4; ++r)
        Pl[w][g * 4 + r][c * 16 + lr] = (bf16)p[c][r];
    bf16x8 ap = *reinterpret_cast<const bf16x8*>(&Pl[w][lr][g * 8]);
#pragma unroll
    for (int t = 0; t < 4; ++t) {
      bf16x8 bv = *reinterpret_cast<const bf16x8*>(&Vt[t * 16 + lr][g * 8]);
      acco[t] = MFMA(ap, bv, acco[t]);
    }
  }

#pragma unroll
  for (int t = 0; t < 4; ++t)
#pragma unroll
    for (int r = 0; r < 4; ++r) {
      int qq = q0 + g * 4 + r;
      Og[((size_t)qq * BATCH + b) * D_MODEL + h * D_K + t * 16 + lr] = acco[t][r] / lrun[r];
    }
}

// ---------------------------------------------------------------------------
__launch_bounds__(256)
__global__ void add_ln(const float* __restrict__ X, const float* __restrict__ Y,
                       const float* __restrict__ gam, const float* __restrict__ bet,
                       float* __restrict__ O) {
  const int row = blockIdx.x, tid = threadIdx.x;
  const int lane = tid & 63, w = tid >> 6;
  __shared__ float red[4];
  float4 x = *reinterpret_cast<const float4*>(&X[(size_t)row * D_MODEL + tid * 4]);
  float4 y = *reinterpret_cast<const float4*>(&Y[(size_t)row * D_MODEL + tid * 4]);
  float v0 = x.x + y.x, v1 = x.y + y.y, v2 = x.z + y.z, v3 = x.w + y.w;
  float sm = v0 + v1 + v2 + v3;
#pragma unroll
  for (int off = 32; off >= 1; off >>= 1) sm += __shfl_xor(sm, off);
  if (lane == 0) red[w] = sm;
  __syncthreads();
  float mu = (red[0] + red[1] + red[2] + red[3]) * (1.f / D_MODEL);
  float d0 = v0 - mu, d1 = v1 - mu, d2 = v2 - mu, d3 = v3 - mu;
  float qs = d0 * d0 + d1 * d1 + d2 * d2 + d3 * d3;
#pragma unroll
  for (int off = 32; off >= 1; off >>= 1) qs += __shfl_xor(qs, off);
  __syncthreads();
  if (lane == 0) red[w] = qs;
  __syncthreads();
  float var = (red[0] + red[1] + red[2] + red[3]) * (1.f / D_MODEL);
  float rs = rsqrtf(var + 1e-5f);
  float4 gv = *reinterpret_cast<const float4*>(&gam[tid * 4]);
  float4 bv = *reinterpret_cast<const float4*>(&bet[tid * 4]);
  float4 o;
  o.x = d0 * rs * gv.x + bv.x;
  o.y = d1 * rs * gv.y + bv.y;
  o.z = d2 * rs * gv.z + bv.z;
  o.w = d3 * rs * gv.w + bv.w;
  *reinterpret_cast<float4*>(&O[(size_t)row * D_MODEL + tid * 4]) = o;
}

// ---------------------------------------------------------------------------
extern "C" void kernel_launch(void* const* d_in, const int* in_sizes, int n_in,
                              void* d_out, int out_size, void* d_ws, size_t ws_size,
                              hipStream_t stream) {
  (void)in_sizes; (void)n_in; (void)out_size; (void)ws_size;
  const float* tgt   = (const float*)d_in[0];
  const float* mem   = (const float*)d_in[1];
  const float* sa_wq = (const float*)d_in[2];
  const float* sa_bq = (const float*)d_in[3];
  const float* sa_wk = (const float*)d_in[4];
  const float* sa_bk = (const float*)d_in[5];
  const float* sa_wv = (const float*)d_in[6];
  const float* sa_bv = (const float*)d_in[7];
  const float* sa_wo = (const float*)d_in[8];
  const float* sa_bo = (const float*)d_in[9];
  const float* ca_wq = (const float*)d_in[10];
  const float* ca_bq = (const float*)d_in[11];
  const float* ca_wk = (const float*)d_in[12];
  const float* ca_bk = (const float*)d_in[13];
  const float* ca_wv = (const float*)d_in[14];
  const float* ca_bv = (const float*)d_in[15];
  const float* ca_wo = (const float*)d_in[16];
  const float* ca_bo = (const float*)d_in[17];
  const float* ff_w1 = (const float*)d_in[18];
  const float* ff_b1 = (const float*)d_in[19];
  const float* ff_w2 = (const float*)d_in[20];
  const float* ff_b2 = (const float*)d_in[21];
  const float* ln1g  = (const float*)d_in[22];
  const float* ln1b  = (const float*)d_in[23];
  const float* ln2g  = (const float*)d_in[24];
  const float* ln2b  = (const float*)d_in[25];
  const float* ln3g  = (const float*)d_in[26];
  const float* ln3b  = (const float*)d_in[27];
  float* out = (float*)d_out;

  bf16* wt = (bf16*)d_ws;
  size_t cur = 0;
  auto walloc = [&](size_t n) { bf16* p = wt + cur; cur += n; return p; };
  const size_t SQ = (size_t)1024 * 1024;
  bf16 *sawq_h = walloc(SQ), *sawq_l = walloc(SQ);
  bf16 *sawk_h = walloc(SQ), *sawk_l = walloc(SQ);
  bf16 *sawv_h = walloc(SQ), *sawv_l = walloc(SQ);
  bf16 *sawo_h = walloc(SQ), *sawo_l = walloc(SQ);
  bf16 *cawq_h = walloc(SQ), *cawq_l = walloc(SQ);
  bf16 *cawk_h = walloc(SQ), *cawk_l = walloc(SQ);
  bf16 *cawv_h = walloc(SQ), *cawv_l = walloc(SQ);
  bf16 *cawo_h = walloc(SQ), *cawo_l = walloc(SQ);
  bf16 *w1_h = walloc(SQ * 4), *w1_l = walloc(SQ * 4);
  bf16 *w2_h = walloc(SQ * 4), *w2_l = walloc(SQ * 4);
  float* fb = (float*)(wt + cur);
  const size_t FB = (size_t)M_ROWS * D_MODEL;
  float* Qb  = fb;
  float* Kb  = fb + FB;
  float* Vb  = fb + 2 * FB;
  float* CTX = fb + 3 * FB;
  float* X1  = fb + 4 * FB;
  float* X2  = fb + 5 * FB;
  float* HC  = fb + 6 * FB;

  dim3 cb(32, 8);
  auto cast_w = [&](const float* W, int K, int N, bf16* th, bf16* tl) {
    hipLaunchKernelGGL(wcast_t, dim3(K / 32, N / 32), cb, 0, stream, W, th, tl, K, N);
  };
  cast_w(sa_wq, 1024, 1024, sawq_h, sawq_l);
  cast_w(sa_wk, 1024, 1024, sawk_h, sawk_l);
  cast_w(sa_wv, 1024, 1024, sawv_h, sawv_l);
  cast_w(sa_wo, 1024, 1024, sawo_h, sawo_l);
  cast_w(ca_wq, 1024, 1024, cawq_h, cawq_l);
  cast_w(ca_wk, 1024, 1024, cawk_h, cawk_l);
  cast_w(ca_wv, 1024, 1024, cawv_h, cawv_l);
  cast_w(ca_wo, 1024, 1024, cawo_h, cawo_l);
  cast_w(ff_w1, 1024, 4096, w1_h, w1_l);
  cast_w(ff_w2, 4096, 1024, w2_h, w2_l);

  auto gemm = [&](const float* A, const bf16* Wh, const bf16* Wl, const float* bias,
                  float* C, int M, int N, int K, int ldw, int flags) {
    hipLaunchKernelGGL(gemm_split, dim3(N / 128, M / 128), dim3(256), 0, stream,
                       A, Wh, Wl, bias, C, M, N, K, ldw, flags);
  };

  // self-attention
  gemm(tgt, sawq_h, sawq_l, sa_bq, Qb, M_ROWS, 1024, 1024, 1024, 0);
  gemm(tgt, sawk_h, sawk_l, sa_bk, Kb, M_ROWS, 1024, 1024, 1024, 0);
  gemm(tgt, sawv_h, sawv_l, sa_bv, Vb, M_ROWS, 1024, 1024, 1024, 0);
  hipLaunchKernelGGL(attn_kernel, dim3(S_LEN / 64, BATCH * NHEAD), dim3(256), 0, stream,
                     Qb, Kb, Vb, CTX, 1);
  gemm(CTX, sawo_h, sawo_l, sa_bo, Qb, M_ROWS, 1024, 1024, 1024, 0);
  hipLaunchKernelGGL(add_ln, dim3(M_ROWS), dim3(256), 0, stream, tgt, Qb, ln1g, ln1b, X1);

  // cross-attention
  gemm(X1, cawq_h, cawq_l, ca_bq, Qb, M_ROWS, 1024, 1024, 1024, 0);
  gemm(mem, cawk_h, cawk_l, ca_bk, Kb, M_ROWS, 1024, 1024, 1024, 0);
  gemm(mem, cawv_h, cawv_l, ca_bv, Vb, M_ROWS, 1024, 1024, 1024, 0);
  hipLaunchKernelGGL(attn_kernel, dim3(S_LEN / 64, BATCH * NHEAD), dim3(256), 0, stream,
                     Qb, Kb, Vb, CTX, 0);
  gemm(CTX, cawo_h, cawo_l, ca_bo, Qb, M_ROWS, 1024, 1024, 1024, 0);
  hipLaunchKernelGGL(add_ln, dim3(M_ROWS), dim3(256), 0, stream, X1, Qb, ln2g, ln2b, X2);

  // FFN, chunked over D_FF (4 x 1024), K-split accumulate into Qb
  for (int c2 = 0; c2 < 4; ++c2) {
    gemm(X2, w1_h + (size_t)c2 * 1024 * 1024, w1_l + (size_t)c2 * 1024 * 1024,
         ff_b1 + c2 * 1024, HC, M_ROWS, 1024, 1024, 1024, 1 /*relu*/);
    gemm(HC, w2_h + c2 * 1024, w2_l + c2 * 1024, ff_b2, Qb,
         M_ROWS, 1024, 1024, 4096, c2 == 0 ? 0 : 2 /*accum*/);
  }
  hipLaunchKernelGGL(add_ln, dim3(M_ROWS), dim3(256), 0, stream, X2, Qb, ln3g, ln3b, out);
}

// Round 3
// 1123.779 us; speedup vs baseline: 1.4564x; 1.4564x over previous
//
#include <hip/hip_runtime.h>
#include <cstdint>
#include <cstddef>

// DecoderBlock on MI355X (gfx950), round 2.
// - All linear layers: 3-pass bf16 hi/lo split MFMA (~fp32 accuracy), m97-style
//   structure: pre-split bf16 operands, global_load_lds staging, 128x128 tile.
// - Activations kept in split-bf16 form end-to-end (producers write h/l).
// - Attention: flash-style, KVBLK=64, 32 q-rows/wave, bf16 in, glds K staging.

typedef __bf16 bf16;
typedef __attribute__((ext_vector_type(4))) float f32x4;
typedef __attribute__((ext_vector_type(8))) __bf16 bf16x8;
typedef __attribute__((ext_vector_type(4))) __bf16 bf16x4;
typedef __attribute__((ext_vector_type(2))) __bf16 bf16x2;

#define MFMA(a, b, c) __builtin_amdgcn_mfma_f32_16x16x32_bf16((a), (b), (c), 0, 0, 0)

constexpr int D_MODEL = 1024;
constexpr int S_LEN   = 2048;
constexpr int BATCH   = 2;
constexpr int M_ROWS  = S_LEN * BATCH;  // 4096

struct bfp { bf16 h, l; };
__device__ __forceinline__ bfp fsplit(float f) {
  bfp r;
  r.h = (bf16)f;
  r.l = (bf16)(f - (float)r.h);
  return r;
}

typedef const void __attribute__((address_space(1))) gas_void;
typedef void __attribute__((address_space(3))) las_void;
__device__ __forceinline__ void glds16(const void* g, void* l) {
  __builtin_amdgcn_global_load_lds((gas_void*)g, (las_void*)l, 16, 0, 0);
}

// ---------------------------------------------------------------------------
// Weight cast + transpose: W[K][N] fp32 -> Th[N][K], Tl[N][K] bf16 hi/lo
// ---------------------------------------------------------------------------
__global__ void wcast_t(const float* __restrict__ W, bf16* __restrict__ Th,
                        bf16* __restrict__ Tl, int K, int N) {
  __shared__ float t[32][33];
  const int kt = blockIdx.x * 32, nt = blockIdx.y * 32;
  const int tx = threadIdx.x, ty = threadIdx.y;  // 32 x 8
#pragma unroll
  for (int i = 0; i < 4; ++i)
    t[ty * 4 + i][tx] = W[(size_t)(kt + ty * 4 + i) * N + nt + tx];
  __syncthreads();
#pragma unroll
  for (int i = 0; i < 4; ++i) {
    int n = nt + ty * 4 + i;
    bfp s = fsplit(t[tx][ty * 4 + i]);
    Th[(size_t)n * K + kt + tx] = s.h;
    Tl[(size_t)n * K + kt + tx] = s.l;
  }
}

// ---------------------------------------------------------------------------
// Elementwise fp32 -> bf16 hi/lo split (for tgt / memory)
// ---------------------------------------------------------------------------
__global__ void act_split(const float* __restrict__ X, bf16* __restrict__ H,
                          bf16* __restrict__ L) {
  const size_t i = ((size_t)blockIdx.x * 256 + threadIdx.x) * 4;
  float4 v = *reinterpret_cast<const float4*>(&X[i]);
  bf16x4 h, l;
  bfp s0 = fsplit(v.x); h[0] = s0.h; l[0] = s0.l;
  bfp s1 = fsplit(v.y); h[1] = s1.h; l[1] = s1.l;
  bfp s2 = fsplit(v.z); h[2] = s2.h; l[2] = s2.l;
  bfp s3 = fsplit(v.w); h[3] = s3.h; l[3] = s3.l;
  *reinterpret_cast<bf16x4*>(&H[i]) = h;
  *reinterpret_cast<bf16x4*>(&L[i]) = l;
}

// ---------------------------------------------------------------------------
// Split GEMM, m97 structure. A = Ah+Al [M][K] bf16, B = Bh+Bl [N][ldb] bf16.
// C = A*B^T(+bias). flags: 1 relu, 2 f32-atomic-acc, 4 bf16 out, 8 split out,
// 16 add bias (z==0 only). K-split via gridDim.z.
// ---------------------------------------------------------------------------
__launch_bounds__(256)
__global__ void gemm_split(const bf16* __restrict__ Ah_g, const bf16* __restrict__ Al_g,
                           const bf16* __restrict__ Bh_g, const bf16* __restrict__ Bl_g,
                           const float* __restrict__ bias,
                           float* Cf, bf16* Ch, bf16* Cl,
                           int N, int K, int ldb, int flags) {
  __shared__ bf16 sAh[4096], sAl[4096], sBh[4096], sBl[4096];  // [128][32] each
  const int tid = threadIdx.x, ln = tid & 63, w = tid >> 6;
  const int g = ln >> 4, lr = ln & 15;
  const int wr = w >> 1, wc = w & 1;
  const int m0 = blockIdx.y * 128, n0 = blockIdx.x * 128;
  const int kz = K / gridDim.z;
  const int kbeg = blockIdx.z * kz, kend = kbeg + kz;

  f32x4 acc[4][4] = {};

  for (int k0 = kbeg; k0 < kend; k0 += 32) {
    __syncthreads();
#pragma unroll
    for (int i = 0; i < 2; ++i) {
      const int r = w * 32 + i * 16 + (ln >> 2);
      const int co = (ln & 3) * 8;
      const int lb = (w * 32 + i * 16) * 32;
      glds16(Ah_g + (size_t)(m0 + r) * K + k0 + co, &sAh[lb]);
      glds16(Al_g + (size_t)(m0 + r) * K + k0 + co, &sAl[lb]);
      glds16(Bh_g + (size_t)(n0 + r) * ldb + k0 + co, &sBh[lb]);
      glds16(Bl_g + (size_t)(n0 + r) * ldb + k0 + co, &sBl[lb]);
    }
    __syncthreads();

    bf16x8 ah[4], al[4], bh[4], bl[4];
#pragma unroll
    for (int mi = 0; mi < 4; ++mi) {
      const int r = wr * 64 + mi * 16 + lr;
      ah[mi] = *reinterpret_cast<const bf16x8*>(&sAh[r * 32 + g * 8]);
      al[mi] = *reinterpret_cast<const bf16x8*>(&sAl[r * 32 + g * 8]);
    }
#pragma unroll
    for (int ni = 0; ni < 4; ++ni) {
      const int r = wc * 64 + ni * 16 + lr;
      bh[ni] = *reinterpret_cast<const bf16x8*>(&sBh[r * 32 + g * 8]);
      bl[ni] = *reinterpret_cast<const bf16x8*>(&sBl[r * 32 + g * 8]);
    }
#pragma unroll
    for (int mi = 0; mi < 4; ++mi)
#pragma unroll
      for (int ni = 0; ni < 4; ++ni) {
        acc[mi][ni] = MFMA(ah[mi], bh[ni], acc[mi][ni]);
        acc[mi][ni] = MFMA(ah[mi], bl[ni], acc[mi][ni]);
        acc[mi][ni] = MFMA(al[mi], bh[ni], acc[mi][ni]);
      }
  }

#pragma unroll
  for (int mi = 0; mi < 4; ++mi)
#pragma unroll
    for (int ni = 0; ni < 4; ++ni) {
      const int col = n0 + wc * 64 + ni * 16 + lr;
      const float bv = ((flags & 16) && blockIdx.z == 0) ? bias[col] : 0.f;
#pragma unroll
      for (int r = 0; r < 4; ++r) {
        const int row = m0 + wr * 64 + mi * 16 + g * 4 + r;
        float v = acc[mi][ni][r] + bv;
        if (flags & 1) v = fmaxf(v, 0.f);
        const size_t off = (size_t)row * N + col;
        if (flags & 2) {
          atomicAdd(&Cf[off], v);
        } else if (flags & 4) {
          Ch[off] = (bf16)v;
        } else if (flags & 8) {
          bfp sp = fsplit(v);
          Ch[off] = sp.h;
          Cl[off] = sp.l;
        } else {
          Cf[off] = v;
        }
      }
    }
}

// ---------------------------------------------------------------------------
// Flash attention, bf16 in, split-bf16 CTX out.
// Q/K/V element (s,b,h,d) at base[(s*BATCH+b)*stride + h*64 + d].
// Grid (S/128, BATCH*NHEAD), 256 threads; wave w owns q-rows q0..q0+31.
// ---------------------------------------------------------------------------
__launch_bounds__(256)
__global__ void attn_kernel(const bf16* __restrict__ Qg, const bf16* __restrict__ Kg,
                            const bf16* __restrict__ Vg, int qs, int kvs,
                            bf16* __restrict__ Ch, bf16* __restrict__ Cl, int causal) {
  __shared__ bf16 Kl[64 * 64];   // [key][d] linear (glds)
  __shared__ bf16 Vt[64][72];    // [d][key], padded
  __shared__ bf16 Pl[4][32][72]; // per-wave P relay
  const int tid = threadIdx.x, ln = tid & 63, w = tid >> 6;
  const int g = ln >> 4, lr = ln & 15;
  const int qt = blockIdx.x, bh = blockIdx.y;
  const int b = bh >> 4, h = bh & 15;
  const int q0 = qt * 128 + w * 32;

  bf16x8 aq[2][2];
#pragma unroll
  for (int mf = 0; mf < 2; ++mf)
#pragma unroll
    for (int kk = 0; kk < 2; ++kk)
      aq[mf][kk] = *reinterpret_cast<const bf16x8*>(
          &Qg[(size_t)((q0 + mf * 16 + lr) * BATCH + b) * qs + h * 64 + kk * 32 + g * 8]);

  f32x4 acco[2][4] = {};
  float mrun[2][4], lrun[2][4];
#pragma unroll
  for (int mf = 0; mf < 2; ++mf)
#pragma unroll
    for (int r = 0; r < 4; ++r) { mrun[mf][r] = -1e30f; lrun[mf][r] = 0.f; }

  const int nkv = causal ? (qt * 2 + 2) : (S_LEN / 64);
  const int dq = tid >> 4, kp = tid & 15;  // V staging
  const int kk8 = ln >> 3, d8 = ln & 7;    // K staging

  for (int kv = 0; kv < nkv; ++kv) {
    const int kv0 = kv * 64;
    __syncthreads();
    // K tile: global_load_lds, linear [64][64]
#pragma unroll
    for (int i = 0; i < 2; ++i) {
      const int key = w * 16 + i * 8 + kk8;
      glds16(Kg + (size_t)((kv0 + key) * BATCH + b) * kvs + h * 64 + d8 * 8,
             &Kl[(w * 16 + i * 8) * 64]);
    }
    // V tile transposed via registers (vectorized bf16x2 writes)
#pragma unroll
    for (int p = 0; p < 2; ++p) {
      const int k0v = kp * 2 + p * 32;
      bf16x4 va = *reinterpret_cast<const bf16x4*>(
          &Vg[(size_t)((kv0 + k0v) * BATCH + b) * kvs + h * 64 + dq * 4]);
      bf16x4 vb = *reinterpret_cast<const bf16x4*>(
          &Vg[(size_t)((kv0 + k0v + 1) * BATCH + b) * kvs + h * 64 + dq * 4]);
#pragma unroll
      for (int i = 0; i < 4; ++i) {
        bf16x2 t2;
        t2[0] = va[i];
        t2[1] = vb[i];
        *reinterpret_cast<bf16x2*>(&Vt[dq * 4 + i][k0v]) = t2;
      }
    }
    __syncthreads();

    if (!(causal && kv0 > q0 + 31)) {
      // S = (Q K^T) * 1/sqrt(64)
      f32x4 s[2][4];
#pragma unroll
      for (int mf = 0; mf < 2; ++mf)
#pragma unroll
        for (int c = 0; c < 4; ++c) {
          f32x4 a = {};
#pragma unroll
          for (int kk = 0; kk < 2; ++kk) {
            bf16x8 bk = *reinterpret_cast<const bf16x8*>(&Kl[(c * 16 + lr) * 64 + kk * 32 + g * 8]);
            a = MFMA(aq[mf][kk], bk, a);
          }
#pragma unroll
          for (int r = 0; r < 4; ++r) a[r] *= 0.125f;
          s[mf][c] = a;
        }
      if (causal) {
#pragma unroll
        for (int mf = 0; mf < 2; ++mf)
#pragma unroll
          for (int c = 0; c < 4; ++c) {
            const int key = kv0 + c * 16 + lr;
#pragma unroll
            for (int r = 0; r < 4; ++r)
              if (key > q0 + mf * 16 + g * 4 + r) s[mf][c][r] = -1e30f;
          }
      }
      // online softmax (rows live on 16 lanes sharing g)
#pragma unroll
      for (int mf = 0; mf < 2; ++mf)
#pragma unroll
        for (int r = 0; r < 4; ++r) {
          float mx = fmaxf(fmaxf(s[mf][0][r], s[mf][1][r]), fmaxf(s[mf][2][r], s[mf][3][r]));
#pragma unroll
          for (int off = 8; off >= 1; off >>= 1) mx = fmaxf(mx, __shfl_xor(mx, off));
          const float mnew = fmaxf(mrun[mf][r], mx);
          const float sf = __expf(mrun[mf][r] - mnew);
          float pv[4], ps = 0.f;
#pragma unroll
          for (int c = 0; c < 4; ++c) { pv[c] = __expf(s[mf][c][r] - mnew); ps += pv[c]; }
#pragma unroll
          for (int off = 8; off >= 1; off >>= 1) ps += __shfl_xor(ps, off);
          lrun[mf][r] = lrun[mf][r] * sf + ps;
          mrun[mf][r] = mnew;
#pragma unroll
          for (int t = 0; t < 4; ++t) acco[mf][t][r] *= sf;
#pragma unroll
          for (int c = 0; c < 4; ++c) Pl[w][mf * 16 + g * 4 + r][c * 16 + lr] = (bf16)pv[c];
        }
      // O += P V
#pragma unroll
      for (int mf = 0; mf < 2; ++mf) {
        bf16x8 ap0 = *reinterpret_cast<const bf16x8*>(&Pl[w][mf * 16 + lr][g * 8]);
        bf16x8 ap1 = *reinterpret_cast<const bf16x8*>(&Pl[w][mf * 16 + lr][32 + g * 8]);
#pragma unroll
        for (int t = 0; t < 4; ++t) {
          bf16x8 v0 = *reinterpret_cast<const bf16x8*>(&Vt[t * 16 + lr][g * 8]);
          bf16x8 v1 = *reinterpret_cast<const bf16x8*>(&Vt[t * 16 + lr][32 + g * 8]);
          acco[mf][t] = MFMA(ap0, v0, acco[mf][t]);
          acco[mf][t] = MFMA(ap1, v1, acco[mf][t]);
        }
      }
    }
  }

#pragma unroll
  for (int mf = 0; mf < 2; ++mf)
#pragma unroll
    for (int t = 0; t < 4; ++t)
#pragma unroll
      for (int r = 0; r < 4; ++r) {
        const int srow = q0 + mf * 16 + g * 4 + r;
        const size_t off = (size_t)(srow * BATCH + b) * D_MODEL + h * 64 + t * 16 + lr;
        const float v = acco[mf][t][r] / lrun[mf][r];
        bfp sp = fsplit(v);
        Ch[off] = sp.h;
        Cl[off] = sp.l;
      }
}

// ---------------------------------------------------------------------------
// Fused residual add + LayerNorm (+ optional split-bf16 output)
// ---------------------------------------------------------------------------
__launch_bounds__(256)
__global__ void add_ln(const float* __restrict__ X, const float* __restrict__ Y,
                       const float* __restrict__ gam, const float* __restrict__ bet,
                       float* __restrict__ O, bf16* __restrict__ Oh, bf16* __restrict__ Ol) {
  const int row = blockIdx.x, tid = threadIdx.x;
  const int lane = tid & 63, w = tid >> 6;
  __shared__ float red[4];
  float4 x = *reinterpret_cast<const float4*>(&X[(size_t)row * D_MODEL + tid * 4]);
  float4 y = *reinterpret_cast<const float4*>(&Y[(size_t)row * D_MODEL + tid * 4]);
  float v0 = x.x + y.x, v1 = x.y + y.y, v2 = x.z + y.z, v3 = x.w + y.w;
  float sm = v0 + v1 + v2 + v3;
#pragma unroll
  for (int off = 32; off >= 1; off >>= 1) sm += __shfl_xor(sm, off);
  if (lane == 0) red[w] = sm;
  __syncthreads();
  float mu = (red[0] + red[1] + red[2] + red[3]) * (1.f / D_MODEL);
  float d0 = v0 - mu, d1 = v1 - mu, d2 = v2 - mu, d3 = v3 - mu;
  float qs = d0 * d0 + d1 * d1 + d2 * d2 + d3 * d3;
#pragma unroll
  for (int off = 32; off >= 1; off >>= 1) qs += __shfl_xor(qs, off);
  __syncthreads();
  if (lane == 0) red[w] = qs;
  __syncthreads();
  float var = (red[0] + red[1] + red[2] + red[3]) * (1.f / D_MODEL);
  float rs = rsqrtf(var + 1e-5f);
  float4 gv = *reinterpret_cast<const float4*>(&gam[tid * 4]);
  float4 bv = *reinterpret_cast<const float4*>(&bet[tid * 4]);
  float4 o;
  o.x = d0 * rs * gv.x + bv.x;
  o.y = d1 * rs * gv.y + bv.y;
  o.z = d2 * rs * gv.z + bv.z;
  o.w = d3 * rs * gv.w + bv.w;
  *reinterpret_cast<float4*>(&O[(size_t)row * D_MODEL + tid * 4]) = o;
  if (Oh) {
    bf16x4 h4, l4;
    bfp s0 = fsplit(o.x); h4[0] = s0.h; l4[0] = s0.l;
    bfp s1 = fsplit(o.y); h4[1] = s1.h; l4[1] = s1.l;
    bfp s2 = fsplit(o.z); h4[2] = s2.h; l4[2] = s2.l;
    bfp s3 = fsplit(o.w); h4[3] = s3.h; l4[3] = s3.l;
    *reinterpret_cast<bf16x4*>(&Oh[(size_t)row * D_MODEL + tid * 4]) = h4;
    *reinterpret_cast<bf16x4*>(&Ol[(size_t)row * D_MODEL + tid * 4]) = l4;
  }
}

// ---------------------------------------------------------------------------
extern "C" void kernel_launch(void* const* d_in, const int* in_sizes, int n_in,
                              void* d_out, int out_size, void* d_ws, size_t ws_size,
                              hipStream_t stream) {
  (void)in_sizes; (void)n_in; (void)out_size; (void)ws_size;
  const float* tgt   = (const float*)d_in[0];
  const float* mem   = (const float*)d_in[1];
  const float* sa_wq = (const float*)d_in[2];
  const float* sa_bq = (const float*)d_in[3];
  const float* sa_wk = (const float*)d_in[4];
  const float* sa_bk = (const float*)d_in[5];
  const float* sa_wv = (const float*)d_in[6];
  const float* sa_bv = (const float*)d_in[7];
  const float* sa_wo = (const float*)d_in[8];
  const float* sa_bo = (const float*)d_in[9];
  const float* ca_wq = (const float*)d_in[10];
  const float* ca_bq = (const float*)d_in[11];
  const float* ca_wk = (const float*)d_in[12];
  const float* ca_bk = (const float*)d_in[13];
  const float* ca_wv = (const float*)d_in[14];
  const float* ca_bv = (const float*)d_in[15];
  const float* ca_wo = (const float*)d_in[16];
  const float* ca_bo = (const float*)d_in[17];
  const float* ff_w1 = (const float*)d_in[18];
  const float* ff_b1 = (const float*)d_in[19];
  const float* ff_w2 = (const float*)d_in[20];
  const float* ff_b2 = (const float*)d_in[21];
  const float* ln1g  = (const float*)d_in[22];
  const float* ln1b  = (const float*)d_in[23];
  const float* ln2g  = (const float*)d_in[24];
  const float* ln2b  = (const float*)d_in[25];
  const float* ln3g  = (const float*)d_in[26];
  const float* ln3b  = (const float*)d_in[27];
  float* out = (float*)d_out;

  char* base = (char*)d_ws;
  const size_t MB = 1u << 20;
  auto B16 = [&](size_t mb) { return (bf16*)(base + mb * MB); };
  auto F32 = [&](size_t mb) { return (float*)(base + mb * MB); };

  // weights (split, [N][K] transposed)
  bf16 *qkvW_h = B16(0),  *qkvW_l = B16(6);
  bf16 *sawo_h = B16(12), *sawo_l = B16(14);
  bf16 *caqW_h = B16(16), *caqW_l = B16(18);
  bf16 *cakv_h = B16(20), *cakv_l = B16(24);
  bf16 *cawo_h = B16(28), *cawo_l = B16(30);
  bf16 *w1_h   = B16(32), *w1_l   = B16(40);
  bf16 *w2_h   = B16(48), *w2_l   = B16(56);
  float* qkv_bias  = F32(64);
  float* cakv_bias = (float*)(base + 64 * MB + 65536);
  // activations
  bf16 *tgt_h = B16(65), *tgt_l = B16(73);   // later X2_hl
  bf16 *mem_h = B16(81), *mem_l = B16(89);
  float* X2f  = F32(81);                     // after mem_hl dead
  bf16 *QKV   = B16(97);                     // [4096][3072]
  bf16 *Qb    = B16(97);                     // CA: [4096][1024]
  bf16 *KVb   = B16(105);                    // CA: [4096][2048]
  bf16 *HC_h  = B16(97), *HC_l = B16(113);   // FFN chunk [4096][2048]
  bf16 *CTX_h = B16(121), *CTX_l = B16(129);
  bf16 *X1_h  = B16(121), *X1_l  = B16(129); // alias CTX (sequenced)
  float* X1f  = F32(137);
  float* ACC  = F32(153);

  dim3 cb(32, 8);
  auto cast_w = [&](const float* W, int K, int N, bf16* th, bf16* tl) {
    hipLaunchKernelGGL(wcast_t, dim3(K / 32, N / 32), cb, 0, stream, W, th, tl, K, N);
  };
  // merged SA QKV weight [3072][1024]
  cast_w(sa_wq, 1024, 1024, qkvW_h, qkvW_l);
  cast_w(sa_wk, 1024, 1024, qkvW_h + (size_t)1024 * 1024, qkvW_l + (size_t)1024 * 1024);
  cast_w(sa_wv, 1024, 1024, qkvW_h + (size_t)2048 * 1024, qkvW_l + (size_t)2048 * 1024);
  cast_w(sa_wo, 1024, 1024, sawo_h, sawo_l);
  cast_w(ca_wq, 1024, 1024, caqW_h, caqW_l);
  cast_w(ca_wk, 1024, 1024, cakv_h, cakv_l);
  cast_w(ca_wv, 1024, 1024, cakv_h + (size_t)1024 * 1024, cakv_l + (size_t)1024 * 1024);
  cast_w(ca_wo, 1024, 1024, cawo_h, cawo_l);
  cast_w(ff_w1, 1024, 4096, w1_h, w1_l);
  cast_w(ff_w2, 4096, 1024, w2_h, w2_l);
  // merged biases
  hipMemcpyAsync(qkv_bias,        sa_bq, 4096, hipMemcpyDeviceToDevice, stream);
  hipMemcpyAsync(qkv_bias + 1024, sa_bk, 4096, hipMemcpyDeviceToDevice, stream);
  hipMemcpyAsync(qkv_bias + 2048, sa_bv, 4096, hipMemcpyDeviceToDevice, stream);
  hipMemcpyAsync(cakv_bias,        ca_bk, 4096, hipMemcpyDeviceToDevice, stream);
  hipMemcpyAsync(cakv_bias + 1024, ca_bv, 4096, hipMemcpyDeviceToDevice, stream);
  // activation splits
  hipLaunchKernelGGL(act_split, dim3(4096), dim3(256), 0, stream, tgt, tgt_h, tgt_l);
  hipLaunchKernelGGL(act_split, dim3(4096), dim3(256), 0, stream, mem, mem_h, mem_l);

  auto gemm = [&](const bf16* ah, const bf16* al, const bf16* bh, const bf16* bl,
                  const float* bias, float* cf, bf16* ch, bf16* cl,
                  int N, int K, int ldb, int flags, int Z) {
    hipLaunchKernelGGL(gemm_split, dim3(N / 128, 32, Z), dim3(256), 0, stream,
                       ah, al, bh, bl, bias, cf, ch, cl, N, K, ldb, flags);
  };
  const size_t FBYTES = (size_t)M_ROWS * D_MODEL * 4;

  // ---- self-attention ----
  gemm(tgt_h, tgt_l, qkvW_h, qkvW_l, qkv_bias, nullptr, QKV, nullptr,
       3072, 1024, 1024, 4 | 16, 1);
  hipLaunchKernelGGL(attn_kernel, dim3(S_LEN / 128, 32), dim3(256), 0, stream,
                     QKV, QKV + 1024, QKV + 2048, 3072, 3072, CTX_h, CTX_l, 1);
  hipMemsetAsync(ACC, 0, FBYTES, stream);
  gemm(CTX_h, CTX_l, sawo_h, sawo_l, sa_bo, ACC, nullptr, nullptr,
       1024, 1024, 1024, 2 | 16, 2);
  hipLaunchKernelGGL(add_ln, dim3(M_ROWS), dim3(256), 0, stream,
                     tgt, ACC, ln1g, ln1b, X1f, X1_h, X1_l);

  // ---- cross-attention ----
  gemm(X1_h, X1_l, caqW_h, caqW_l, ca_bq, nullptr, Qb, nullptr,
       1024, 1024, 1024, 4 | 16, 1);
  gemm(mem_h, mem_l, cakv_h, cakv_l, cakv_bias, nullptr, KVb, nullptr,
       2048, 1024, 1024, 4 | 16, 1);
  hipLaunchKernelGGL(attn_kernel, dim3(S_LEN / 128, 32), dim3(256), 0, stream,
                     Qb, KVb, KVb + 1024, 1024, 2048, CTX_h, CTX_l, 0);
  hipMemsetAsync(ACC, 0, FBYTES, stream);
  gemm(CTX_h, CTX_l, cawo_h, cawo_l, ca_bo, ACC, nullptr, nullptr,
       1024, 1024, 1024, 2 | 16, 2);
  hipLaunchKernelGGL(add_ln, dim3(M_ROWS), dim3(256), 0, stream,
                     X1f, ACC, ln2g, ln2b, X2f, tgt_h, tgt_l);  // X2_hl -> tgt_hl region

  // ---- FFN: 2 chunks of D_FF=2048; W2 K-split z=2, atomic accumulate ----
  hipMemsetAsync(ACC, 0, FBYTES, stream);
  for (int c = 0; c < 2; ++c) {
    gemm(tgt_h, tgt_l, w1_h + (size_t)c * 2048 * 1024, w1_l + (size_t)c * 2048 * 1024,
         ff_b1 + c * 2048, nullptr, HC_h, HC_l, 2048, 1024, 1024, 8 | 16 | 1, 1);
    gemm(HC_h, HC_l, w2_h + (size_t)c * 2048, w2_l + (size_t)c * 2048,
         ff_b2, ACC, nullptr, nullptr, 1024, 2048, 4096, 2 | (c == 0 ? 16 : 0), 2);
  }
  hipLaunchKernelGGL(add_ln, dim3(M_ROWS), dim3(256), 0, stream,
                     X2f, ACC, ln3g, ln3b, out, nullptr, nullptr);
}

// Round 4
// 1033.507 us; speedup vs baseline: 1.5836x; 1.0873x over previous
//
#include <hip/hip_runtime.h>
#include <cstdint>
#include <cstddef>

// DecoderBlock on MI355X (gfx950), round 4.
// - Linear layers: 2-pass bf16 split MFMA (A = Ah+Al exact, W = bf16(W)):
//   error ~2.6e-3/layer. m97 structure: global_load_lds staging, 128x128 tile.
// - Attention: QBLK=64, KVBLK=64, double-buffered K/V, ONE barrier per kv
//   iter, XOR-swizzled K tile (pre-swizzled global source, rule #21).

typedef __bf16 bf16;
typedef __attribute__((ext_vector_type(4))) float f32x4;
typedef __attribute__((ext_vector_type(8))) __bf16 bf16x8;
typedef __attribute__((ext_vector_type(4))) __bf16 bf16x4;
typedef __attribute__((ext_vector_type(2))) __bf16 bf16x2;

#define MFMA(a, b, c) __builtin_amdgcn_mfma_f32_16x16x32_bf16((a), (b), (c), 0, 0, 0)

constexpr int D_MODEL = 1024;
constexpr int S_LEN   = 2048;
constexpr int BATCH   = 2;
constexpr int M_ROWS  = S_LEN * BATCH;  // 4096

struct bfp { bf16 h, l; };
__device__ __forceinline__ bfp fsplit(float f) {
  bfp r;
  r.h = (bf16)f;
  r.l = (bf16)(f - (float)r.h);
  return r;
}

typedef const void __attribute__((address_space(1))) gas_void;
typedef void __attribute__((address_space(3))) las_void;
__device__ __forceinline__ void glds16(const void* g, void* l) {
  __builtin_amdgcn_global_load_lds((gas_void*)g, (las_void*)l, 16, 0, 0);
}

// ---------------------------------------------------------------------------
// Weight cast + transpose: W[K][N] fp32 -> Th[N][K] bf16 (hi only, 2-pass)
// ---------------------------------------------------------------------------
__global__ void wcast_t(const float* __restrict__ W, bf16* __restrict__ Th,
                        int K, int N) {
  __shared__ float t[32][33];
  const int kt = blockIdx.x * 32, nt = blockIdx.y * 32;
  const int tx = threadIdx.x, ty = threadIdx.y;  // 32 x 8
#pragma unroll
  for (int i = 0; i < 4; ++i)
    t[ty * 4 + i][tx] = W[(size_t)(kt + ty * 4 + i) * N + nt + tx];
  __syncthreads();
#pragma unroll
  for (int i = 0; i < 4; ++i) {
    int n = nt + ty * 4 + i;
    Th[(size_t)n * K + kt + tx] = (bf16)t[tx][ty * 4 + i];
  }
}

// ---------------------------------------------------------------------------
// Elementwise fp32 -> bf16 hi/lo split (for tgt / memory)
// ---------------------------------------------------------------------------
__global__ void act_split(const float* __restrict__ X, bf16* __restrict__ H,
                          bf16* __restrict__ L) {
  const size_t i = ((size_t)blockIdx.x * 256 + threadIdx.x) * 4;
  float4 v = *reinterpret_cast<const float4*>(&X[i]);
  bf16x4 h, l;
  bfp s0 = fsplit(v.x); h[0] = s0.h; l[0] = s0.l;
  bfp s1 = fsplit(v.y); h[1] = s1.h; l[1] = s1.l;
  bfp s2 = fsplit(v.z); h[2] = s2.h; l[2] = s2.l;
  bfp s3 = fsplit(v.w); h[3] = s3.h; l[3] = s3.l;
  *reinterpret_cast<bf16x4*>(&H[i]) = h;
  *reinterpret_cast<bf16x4*>(&L[i]) = l;
}

// ---------------------------------------------------------------------------
// 2-pass split GEMM. A = Ah+Al [M][K] bf16, B = Bh [N][ldb] bf16 (transposed).
// C = A*B^T(+bias). flags: 1 relu, 2 f32-atomic-acc, 4 bf16 out, 8 split out,
// 16 add bias (z==0 only). K-split via gridDim.z.
// ---------------------------------------------------------------------------
__launch_bounds__(256)
__global__ void gemm_split(const bf16* __restrict__ Ah_g, const bf16* __restrict__ Al_g,
                           const bf16* __restrict__ Bh_g,
                           const float* __restrict__ bias,
                           float* Cf, bf16* Ch, bf16* Cl,
                           int N, int K, int ldb, int flags) {
  __shared__ bf16 sAh[4096], sAl[4096], sBh[4096];  // [128][32] each
  const int tid = threadIdx.x, ln = tid & 63, w = tid >> 6;
  const int g = ln >> 4, lr = ln & 15;
  const int wr = w >> 1, wc = w & 1;
  const int m0 = blockIdx.y * 128, n0 = blockIdx.x * 128;
  const int kz = K / gridDim.z;
  const int kbeg = blockIdx.z * kz, kend = kbeg + kz;

  f32x4 acc[4][4] = {};

  for (int k0 = kbeg; k0 < kend; k0 += 32) {
    __syncthreads();
#pragma unroll
    for (int i = 0; i < 2; ++i) {
      const int r = w * 32 + i * 16 + (ln >> 2);
      const int co = (ln & 3) * 8;
      const int lb = (w * 32 + i * 16) * 32;
      glds16(Ah_g + (size_t)(m0 + r) * K + k0 + co, &sAh[lb]);
      glds16(Al_g + (size_t)(m0 + r) * K + k0 + co, &sAl[lb]);
      glds16(Bh_g + (size_t)(n0 + r) * ldb + k0 + co, &sBh[lb]);
    }
    __syncthreads();

    bf16x8 ah[4], al[4], bh[4];
#pragma unroll
    for (int mi = 0; mi < 4; ++mi) {
      const int r = wr * 64 + mi * 16 + lr;
      ah[mi] = *reinterpret_cast<const bf16x8*>(&sAh[r * 32 + g * 8]);
      al[mi] = *reinterpret_cast<const bf16x8*>(&sAl[r * 32 + g * 8]);
    }
#pragma unroll
    for (int ni = 0; ni < 4; ++ni) {
      const int r = wc * 64 + ni * 16 + lr;
      bh[ni] = *reinterpret_cast<const bf16x8*>(&sBh[r * 32 + g * 8]);
    }
#pragma unroll
    for (int mi = 0; mi < 4; ++mi)
#pragma unroll
      for (int ni = 0; ni < 4; ++ni) {
        acc[mi][ni] = MFMA(ah[mi], bh[ni], acc[mi][ni]);
        acc[mi][ni] = MFMA(al[mi], bh[ni], acc[mi][ni]);
      }
  }

#pragma unroll
  for (int mi = 0; mi < 4; ++mi)
#pragma unroll
    for (int ni = 0; ni < 4; ++ni) {
      const int col = n0 + wc * 64 + ni * 16 + lr;
      const float bv = ((flags & 16) && blockIdx.z == 0) ? bias[col] : 0.f;
#pragma unroll
      for (int r = 0; r < 4; ++r) {
        const int row = m0 + wr * 64 + mi * 16 + g * 4 + r;
        float v = acc[mi][ni][r] + bv;
        if (flags & 1) v = fmaxf(v, 0.f);
        const size_t off = (size_t)row * N + col;
        if (flags & 2) {
          atomicAdd(&Cf[off], v);
        } else if (flags & 4) {
          Ch[off] = (bf16)v;
        } else if (flags & 8) {
          bfp sp = fsplit(v);
          Ch[off] = sp.h;
          Cl[off] = sp.l;
        } else {
          Cf[off] = v;
        }
      }
    }
}

// ---------------------------------------------------------------------------
// Flash attention. bf16 in, split-bf16 CTX out.
// Q/K/V element (s,b,h,d) at base[(s*BATCH+b)*stride + h*64 + d].
// Grid (S/64, BATCH*NHEAD), 256 thr. Wave w owns 16 q-rows q0 = qt*64+w*16.
// Double-buffered K/V, one barrier per kv iter. K tile XOR-swizzled:
// LDS holds K[row][chunk ^ (row&7)] (chunk = 16B unit); glds dest stays
// linear, global source pre-swizzled (rule #21).
// ---------------------------------------------------------------------------
__launch_bounds__(256)
__global__ void attn_kernel(const bf16* __restrict__ Qg, const bf16* __restrict__ Kg,
                            const bf16* __restrict__ Vg, int qs, int kvs,
                            bf16* __restrict__ Ch, bf16* __restrict__ Cl, int causal) {
  __shared__ bf16 Kl[2][64 * 64];   // swizzled, glds
  __shared__ bf16 Vt[2][64][72];    // [d][key], padded
  __shared__ bf16 Pl[4][16][72];    // per-wave P relay
  const int tid = threadIdx.x, ln = tid & 63, w = tid >> 6;
  const int g = ln >> 4, lr = ln & 15;
  const int qt = blockIdx.x, bh = blockIdx.y;
  const int b = bh >> 4, h = bh & 15;
  const int q0 = qt * 64 + w * 16;

  const int krow8 = ln >> 3, d8 = ln & 7;   // K staging
  const int dq = tid >> 4, kp = tid & 15;   // V staging

  bf16x8 aq[2];
#pragma unroll
  for (int kk = 0; kk < 2; ++kk)
    aq[kk] = *reinterpret_cast<const bf16x8*>(
        &Qg[((size_t)(q0 + lr) * BATCH + b) * qs + h * 64 + kk * 32 + g * 8]);

  f32x4 acco[4] = {};
  float mrun[4], lrun[4];
#pragma unroll
  for (int r = 0; r < 4; ++r) { mrun[r] = -1e30f; lrun[r] = 0.f; }

  const int nkv = causal ? (qt + 1) : (S_LEN / 64);

  bf16x4 vreg[2][2];
  auto stageK = [&](int kv0, bf16* dst) {
#pragma unroll
    for (int i = 0; i < 2; ++i) {
      const int rbase = i * 32 + w * 8;
      const int row = rbase + krow8;
      glds16(Kg + (size_t)((kv0 + row) * BATCH + b) * kvs + h * 64 + ((d8 ^ (row & 7)) << 3),
             dst + rbase * 64);
    }
  };
  auto loadV = [&](int kv0) {
#pragma unroll
    for (int p = 0; p < 2; ++p) {
      const int k0v = p * 32 + kp * 2;
      vreg[p][0] = *reinterpret_cast<const bf16x4*>(
          &Vg[(size_t)((kv0 + k0v) * BATCH + b) * kvs + h * 64 + dq * 4]);
      vreg[p][1] = *reinterpret_cast<const bf16x4*>(
          &Vg[(size_t)((kv0 + k0v + 1) * BATCH + b) * kvs + h * 64 + dq * 4]);
    }
  };
  auto writeV = [&](int buf) {
#pragma unroll
    for (int p = 0; p < 2; ++p) {
      const int k0v = p * 32 + kp * 2;
#pragma unroll
      for (int i = 0; i < 4; ++i) {
        bf16x2 t2;
        t2[0] = vreg[p][0][i];
        t2[1] = vreg[p][1][i];
        *reinterpret_cast<bf16x2*>(&Vt[buf][dq * 4 + i][k0v]) = t2;
      }
    }
  };

  // prologue
  stageK(0, Kl[0]);
  loadV(0);
  writeV(0);
  __syncthreads();

  for (int kv = 0; kv < nkv; ++kv) {
    const int cur = kv & 1;
    const bool pre = (kv + 1 < nkv);
    if (pre) {                         // issue next-tile loads early (T14)
      stageK((kv + 1) * 64, Kl[cur ^ 1]);
      loadV((kv + 1) * 64);
    }
    const int kv0 = kv * 64;
    const char* kbase = (const char*)Kl[cur];

    // S = (Q K^T) * 0.125, swizzled K reads
    f32x4 s[4];
#pragma unroll
    for (int c = 0; c < 4; ++c) {
      f32x4 a = {};
#pragma unroll
      for (int kk = 0; kk < 2; ++kk) {
        bf16x8 bk = *reinterpret_cast<const bf16x8*>(
            kbase + (c * 16 + lr) * 128 + ((((kk << 2) + g) ^ (lr & 7)) << 4));
        a = MFMA(aq[kk], bk, a);
      }
#pragma unroll
      for (int r = 0; r < 4; ++r) a[r] *= 0.125f;
      s[c] = a;
    }
    if (causal && kv == qt) {
#pragma unroll
      for (int c = 0; c < 4; ++c) {
        const int key = kv0 + c * 16 + lr;
#pragma unroll
        for (int r = 0; r < 4; ++r)
          if (key > q0 + g * 4 + r) s[c][r] = -1e30f;
      }
    }

    // online softmax (row r of this wave lives on the 16 lanes sharing g)
#pragma unroll
    for (int r = 0; r < 4; ++r) {
      float mx = fmaxf(fmaxf(s[0][r], s[1][r]), fmaxf(s[2][r], s[3][r]));
#pragma unroll
      for (int off = 8; off >= 1; off >>= 1) mx = fmaxf(mx, __shfl_xor(mx, off));
      const float mnew = fmaxf(mrun[r], mx);
      const float sf = __expf(mrun[r] - mnew);
      float pv[4], ps = 0.f;
#pragma unroll
      for (int c = 0; c < 4; ++c) { pv[c] = __expf(s[c][r] - mnew); ps += pv[c]; }
#pragma unroll
      for (int off = 8; off >= 1; off >>= 1) ps += __shfl_xor(ps, off);
      lrun[r] = lrun[r] * sf + ps;
      mrun[r] = mnew;
#pragma unroll
      for (int t = 0; t < 4; ++t) acco[t][r] *= sf;
#pragma unroll
      for (int c = 0; c < 4; ++c) Pl[w][g * 4 + r][c * 16 + lr] = (bf16)pv[c];
    }

    // O += P V
    bf16x8 ap0 = *reinterpret_cast<const bf16x8*>(&Pl[w][lr][g * 8]);
    bf16x8 ap1 = *reinterpret_cast<const bf16x8*>(&Pl[w][lr][32 + g * 8]);
#pragma unroll
    for (int t = 0; t < 4; ++t) {
      bf16x8 v0 = *reinterpret_cast<const bf16x8*>(&Vt[cur][t * 16 + lr][g * 8]);
      bf16x8 v1 = *reinterpret_cast<const bf16x8*>(&Vt[cur][t * 16 + lr][32 + g * 8]);
      acco[t] = MFMA(ap0, v0, acco[t]);
      acco[t] = MFMA(ap1, v1, acco[t]);
    }

    if (pre) writeV(cur ^ 1);  // write-late: HBM latency hidden under compute
    __syncthreads();
  }

#pragma unroll
  for (int t = 0; t < 4; ++t)
#pragma unroll
    for (int r = 0; r < 4; ++r) {
      const int srow = q0 + g * 4 + r;
      const size_t off = (size_t)(srow * BATCH + b) * D_MODEL + h * 64 + t * 16 + lr;
      const float v = acco[t][r] / lrun[r];
      bfp sp = fsplit(v);
      Ch[off] = sp.h;
      Cl[off] = sp.l;
    }
}

// ---------------------------------------------------------------------------
// Fused residual add + LayerNorm (+ optional split-bf16 output)
// ---------------------------------------------------------------------------
__launch_bounds__(256)
__global__ void add_ln(const float* __restrict__ X, const float* __restrict__ Y,
                       const float* __restrict__ gam, const float* __restrict__ bet,
                       float* __restrict__ O, bf16* __restrict__ Oh, bf16* __restrict__ Ol) {
  const int row = blockIdx.x, tid = threadIdx.x;
  const int lane = tid & 63, w = tid >> 6;
  __shared__ float red[4];
  float4 x = *reinterpret_cast<const float4*>(&X[(size_t)row * D_MODEL + tid * 4]);
  float4 y = *reinterpret_cast<const float4*>(&Y[(size_t)row * D_MODEL + tid * 4]);
  float v0 = x.x + y.x, v1 = x.y + y.y, v2 = x.z + y.z, v3 = x.w + y.w;
  float sm = v0 + v1 + v2 + v3;
#pragma unroll
  for (int off = 32; off >= 1; off >>= 1) sm += __shfl_xor(sm, off);
  if (lane == 0) red[w] = sm;
  __syncthreads();
  float mu = (red[0] + red[1] + red[2] + red[3]) * (1.f / D_MODEL);
  float d0 = v0 - mu, d1 = v1 - mu, d2 = v2 - mu, d3 = v3 - mu;
  float qs = d0 * d0 + d1 * d1 + d2 * d2 + d3 * d3;
#pragma unroll
  for (int off = 32; off >= 1; off >>= 1) qs += __shfl_xor(qs, off);
  __syncthreads();
  if (lane == 0) red[w] = qs;
  __syncthreads();
  float var = (red[0] + red[1] + red[2] + red[3]) * (1.f / D_MODEL);
  float rs = rsqrtf(var + 1e-5f);
  float4 gv = *reinterpret_cast<const float4*>(&gam[tid * 4]);
  float4 bv = *reinterpret_cast<const float4*>(&bet[tid * 4]);
  float4 o;
  o.x = d0 * rs * gv.x + bv.x;
  o.y = d1 * rs * gv.y + bv.y;
  o.z = d2 * rs * gv.z + bv.z;
  o.w = d3 * rs * gv.w + bv.w;
  *reinterpret_cast<float4*>(&O[(size_t)row * D_MODEL + tid * 4]) = o;
  if (Oh) {
    bf16x4 h4, l4;
    bfp s0 = fsplit(o.x); h4[0] = s0.h; l4[0] = s0.l;
    bfp s1 = fsplit(o.y); h4[1] = s1.h; l4[1] = s1.l;
    bfp s2 = fsplit(o.z); h4[2] = s2.h; l4[2] = s2.l;
    bfp s3 = fsplit(o.w); h4[3] = s3.h; l4[3] = s3.l;
    *reinterpret_cast<bf16x4*>(&Oh[(size_t)row * D_MODEL + tid * 4]) = h4;
    *reinterpret_cast<bf16x4*>(&Ol[(size_t)row * D_MODEL + tid * 4]) = l4;
  }
}

// ---------------------------------------------------------------------------
extern "C" void kernel_launch(void* const* d_in, const int* in_sizes, int n_in,
                              void* d_out, int out_size, void* d_ws, size_t ws_size,
                              hipStream_t stream) {
  (void)in_sizes; (void)n_in; (void)out_size; (void)ws_size;
  const float* tgt   = (const float*)d_in[0];
  const float* mem   = (const float*)d_in[1];
  const float* sa_wq = (const float*)d_in[2];
  const float* sa_bq = (const float*)d_in[3];
  const float* sa_wk = (const float*)d_in[4];
  const float* sa_bk = (const float*)d_in[5];
  const float* sa_wv = (const float*)d_in[6];
  const float* sa_bv = (const float*)d_in[7];
  const float* sa_wo = (const float*)d_in[8];
  const float* sa_bo = (const float*)d_in[9];
  const float* ca_wq = (const float*)d_in[10];
  const float* ca_bq = (const float*)d_in[11];
  const float* ca_wk = (const float*)d_in[12];
  const float* ca_bk = (const float*)d_in[13];
  const float* ca_wv = (const float*)d_in[14];
  const float* ca_bv = (const float*)d_in[15];
  const float* ca_wo = (const float*)d_in[16];
  const float* ca_bo = (const float*)d_in[17];
  const float* ff_w1 = (const float*)d_in[18];
  const float* ff_b1 = (const float*)d_in[19];
  const float* ff_w2 = (const float*)d_in[20];
  const float* ff_b2 = (const float*)d_in[21];
  const float* ln1g  = (const float*)d_in[22];
  const float* ln1b  = (const float*)d_in[23];
  const float* ln2g  = (const float*)d_in[24];
  const float* ln2b  = (const float*)d_in[25];
  const float* ln3g  = (const float*)d_in[26];
  const float* ln3b  = (const float*)d_in[27];
  float* out = (float*)d_out;

  char* base = (char*)d_ws;
  const size_t MB = 1u << 20;
  auto B16 = [&](size_t mb) { return (bf16*)(base + mb * MB); };
  auto F32 = [&](size_t mb) { return (float*)(base + mb * MB); };

  // weights (bf16 hi only, [N][K] transposed)
  bf16 *qkvW_h  = B16(0);    // 6 MB
  bf16 *sawo_h  = B16(6);    // 2
  bf16 *caqW_h  = B16(8);    // 2
  bf16 *cakvW_h = B16(10);   // 4
  bf16 *cawo_h  = B16(14);   // 2
  bf16 *w1_h    = B16(16);   // 8
  bf16 *w2_h    = B16(24);   // 8
  float* qkv_bias  = F32(32);
  float* cakv_bias = (float*)(base + 32 * MB + 65536);
  // activations
  bf16 *tgt_h = B16(33), *tgt_l = B16(41);   // later X2_hl
  bf16 *mem_h = B16(49), *mem_l = B16(57);
  float* X2f  = F32(49);                     // after mem_hl dead
  bf16 *QKV   = B16(65);                     // [4096][3072]
  bf16 *Qb    = B16(65);                     // CA: [4096][1024]
  bf16 *KVb   = B16(73);                     // CA: [4096][2048]
  bf16 *HC_h  = B16(65), *HC_l = B16(81);    // FFN chunk [4096][2048]
  bf16 *CTX_h = B16(97), *CTX_l = B16(105);  // also X1_hl (sequenced)
  float* X1f  = F32(113);
  float* ACC  = F32(129);

  dim3 cb(32, 8);
  auto cast_w = [&](const float* W, int K, int N, bf16* th) {
    hipLaunchKernelGGL(wcast_t, dim3(K / 32, N / 32), cb, 0, stream, W, th, K, N);
  };
  cast_w(sa_wq, 1024, 1024, qkvW_h);
  cast_w(sa_wk, 1024, 1024, qkvW_h + (size_t)1024 * 1024);
  cast_w(sa_wv, 1024, 1024, qkvW_h + (size_t)2048 * 1024);
  cast_w(sa_wo, 1024, 1024, sawo_h);
  cast_w(ca_wq, 1024, 1024, caqW_h);
  cast_w(ca_wk, 1024, 1024, cakvW_h);
  cast_w(ca_wv, 1024, 1024, cakvW_h + (size_t)1024 * 1024);
  cast_w(ca_wo, 1024, 1024, cawo_h);
  cast_w(ff_w1, 1024, 4096, w1_h);
  cast_w(ff_w2, 4096, 1024, w2_h);
  hipMemcpyAsync(qkv_bias,        sa_bq, 4096, hipMemcpyDeviceToDevice, stream);
  hipMemcpyAsync(qkv_bias + 1024, sa_bk, 4096, hipMemcpyDeviceToDevice, stream);
  hipMemcpyAsync(qkv_bias + 2048, sa_bv, 4096, hipMemcpyDeviceToDevice, stream);
  hipMemcpyAsync(cakv_bias,        ca_bk, 4096, hipMemcpyDeviceToDevice, stream);
  hipMemcpyAsync(cakv_bias + 1024, ca_bv, 4096, hipMemcpyDeviceToDevice, stream);
  hipLaunchKernelGGL(act_split, dim3(4096), dim3(256), 0, stream, tgt, tgt_h, tgt_l);
  hipLaunchKernelGGL(act_split, dim3(4096), dim3(256), 0, stream, mem, mem_h, mem_l);

  auto gemm = [&](const bf16* ah, const bf16* al, const bf16* bh,
                  const float* bias, float* cf, bf16* ch, bf16* cl,
                  int N, int K, int ldb, int flags, int Z) {
    hipLaunchKernelGGL(gemm_split, dim3(N / 128, 32, Z), dim3(256), 0, stream,
                       ah, al, bh, bias, cf, ch, cl, N, K, ldb, flags);
  };
  const size_t FBYTES = (size_t)M_ROWS * D_MODEL * 4;

  // ---- self-attention ----
  gemm(tgt_h, tgt_l, qkvW_h, qkv_bias, nullptr, QKV, nullptr, 3072, 1024, 1024, 4 | 16, 1);
  hipLaunchKernelGGL(attn_kernel, dim3(S_LEN / 64, 32), dim3(256), 0, stream,
                     QKV, QKV + 1024, QKV + 2048, 3072, 3072, CTX_h, CTX_l, 1);
  hipMemsetAsync(ACC, 0, FBYTES, stream);
  gemm(CTX_h, CTX_l, sawo_h, sa_bo, ACC, nullptr, nullptr, 1024, 1024, 1024, 2 | 16, 2);
  hipLaunchKernelGGL(add_ln, dim3(M_ROWS), dim3(256), 0, stream,
                     tgt, ACC, ln1g, ln1b, X1f, CTX_h, CTX_l);  // X1_hl -> CTX bufs

  // ---- cross-attention ----
  gemm(CTX_h, CTX_l, caqW_h, ca_bq, nullptr, Qb, nullptr, 1024, 1024, 1024, 4 | 16, 1);
  gemm(mem_h, mem_l, cakvW_h, cakv_bias, nullptr, KVb, nullptr, 2048, 1024, 1024, 4 | 16, 1);
  hipLaunchKernelGGL(attn_kernel, dim3(S_LEN / 64, 32), dim3(256), 0, stream,
                     Qb, KVb, KVb + 1024, 1024, 2048, CTX_h, CTX_l, 0);
  hipMemsetAsync(ACC, 0, FBYTES, stream);
  gemm(CTX_h, CTX_l, cawo_h, ca_bo, ACC, nullptr, nullptr, 1024, 1024, 1024, 2 | 16, 2);
  hipLaunchKernelGGL(add_ln, dim3(M_ROWS), dim3(256), 0, stream,
                     X1f, ACC, ln2g, ln2b, X2f, tgt_h, tgt_l);  // X2_hl -> tgt bufs

  // ---- FFN: 2 chunks of D_FF=2048; W2 K-split z=2, atomic accumulate ----
  hipMemsetAsync(ACC, 0, FBYTES, stream);
  for (int c = 0; c < 2; ++c) {
    gemm(tgt_h, tgt_l, w1_h + (size_t)c * 2048 * 1024, ff_b1 + c * 2048,
         nullptr, HC_h, HC_l, 2048, 1024, 1024, 8 | 16 | 1, 1);
    gemm(HC_h, HC_l, w2_h + c * 2048, ff_b2, ACC, nullptr, nullptr,
         1024, 2048, 4096, 2 | (c == 0 ? 16 : 0), 2);
  }
  hipLaunchKernelGGL(add_ln, dim3(M_ROWS), dim3(256), 0, stream,
                     X2f, ACC, ln3g, ln3b, out, nullptr, nullptr);
}

// Round 5
// 937.694 us; speedup vs baseline: 1.7454x; 1.1022x over previous
//
#include <hip/hip_runtime.h>
#include <cstdint>
#include <cstddef>

// DecoderBlock on MI355X (gfx950), round 5.
// - Linear layers: 2-pass bf16 split MFMA (A = Ah+Al exact, W = bf16(W)).
//   m97 structure: global_load_lds staging, 128x128 tile.
// - Attention: QBLK=128 (32 rows/wave), KVBLK=64, double-buffered K/V, one
//   barrier per kv iter, XOR-swizzled K (rule #21), Pl stride-68 (conflict
//   fix), deferred l-reduction, setprio around MFMA.
// - Wo projections: K-split z=2 partial stores (no atomics), 3-input add_ln.

typedef __bf16 bf16;
typedef __attribute__((ext_vector_type(4))) float f32x4;
typedef __attribute__((ext_vector_type(8))) __bf16 bf16x8;
typedef __attribute__((ext_vector_type(4))) __bf16 bf16x4;
typedef __attribute__((ext_vector_type(2))) __bf16 bf16x2;

#define MFMA(a, b, c) __builtin_amdgcn_mfma_f32_16x16x32_bf16((a), (b), (c), 0, 0, 0)

constexpr int D_MODEL = 1024;
constexpr int S_LEN   = 2048;
constexpr int BATCH   = 2;
constexpr int M_ROWS  = S_LEN * BATCH;  // 4096

struct bfp { bf16 h, l; };
__device__ __forceinline__ bfp fsplit(float f) {
  bfp r;
  r.h = (bf16)f;
  r.l = (bf16)(f - (float)r.h);
  return r;
}

typedef const void __attribute__((address_space(1))) gas_void;
typedef void __attribute__((address_space(3))) las_void;
__device__ __forceinline__ void glds16(const void* g, void* l) {
  __builtin_amdgcn_global_load_lds((gas_void*)g, (las_void*)l, 16, 0, 0);
}

// ---------------------------------------------------------------------------
// Weight cast + transpose: W[K][N] fp32 -> Th[N][K] bf16
// ---------------------------------------------------------------------------
__global__ void wcast_t(const float* __restrict__ W, bf16* __restrict__ Th,
                        int K, int N) {
  __shared__ float t[32][33];
  const int kt = blockIdx.x * 32, nt = blockIdx.y * 32;
  const int tx = threadIdx.x, ty = threadIdx.y;  // 32 x 8
#pragma unroll
  for (int i = 0; i < 4; ++i)
    t[ty * 4 + i][tx] = W[(size_t)(kt + ty * 4 + i) * N + nt + tx];
  __syncthreads();
#pragma unroll
  for (int i = 0; i < 4; ++i) {
    int n = nt + ty * 4 + i;
    Th[(size_t)n * K + kt + tx] = (bf16)t[tx][ty * 4 + i];
  }
}

// ---------------------------------------------------------------------------
// Elementwise fp32 -> bf16 hi/lo split
// ---------------------------------------------------------------------------
__global__ void act_split(const float* __restrict__ X, bf16* __restrict__ H,
                          bf16* __restrict__ L) {
  const size_t i = ((size_t)blockIdx.x * 256 + threadIdx.x) * 4;
  float4 v = *reinterpret_cast<const float4*>(&X[i]);
  bf16x4 h, l;
  bfp s0 = fsplit(v.x); h[0] = s0.h; l[0] = s0.l;
  bfp s1 = fsplit(v.y); h[1] = s1.h; l[1] = s1.l;
  bfp s2 = fsplit(v.z); h[2] = s2.h; l[2] = s2.l;
  bfp s3 = fsplit(v.w); h[3] = s3.h; l[3] = s3.l;
  *reinterpret_cast<bf16x4*>(&H[i]) = h;
  *reinterpret_cast<bf16x4*>(&L[i]) = l;
}

// ---------------------------------------------------------------------------
// 2-pass split GEMM. A = Ah+Al [M][K] bf16, B = Bh [N][ldb] bf16 (transposed).
// flags: 1 relu, 2 f32-atomic-acc, 4 bf16 out, 8 split out, 16 add bias
// (z==0 only), 32 z-partial store to Cf + z*M*N. K-split via gridDim.z.
// ---------------------------------------------------------------------------
__launch_bounds__(256)
__global__ void gemm_split(const bf16* __restrict__ Ah_g, const bf16* __restrict__ Al_g,
                           const bf16* __restrict__ Bh_g,
                           const float* __restrict__ bias,
                           float* Cf, bf16* Ch, bf16* Cl,
                           int N, int K, int ldb, int flags) {
  __shared__ bf16 sAh[4096], sAl[4096], sBh[4096];  // [128][32] each
  const int tid = threadIdx.x, ln = tid & 63, w = tid >> 6;
  const int g = ln >> 4, lr = ln & 15;
  const int wr = w >> 1, wc = w & 1;
  const int m0 = blockIdx.y * 128, n0 = blockIdx.x * 128;
  const int kz = K / gridDim.z;
  const int kbeg = blockIdx.z * kz, kend = kbeg + kz;

  f32x4 acc[4][4] = {};

  for (int k0 = kbeg; k0 < kend; k0 += 32) {
    __syncthreads();
#pragma unroll
    for (int i = 0; i < 2; ++i) {
      const int r = w * 32 + i * 16 + (ln >> 2);
      const int co = (ln & 3) * 8;
      const int lb = (w * 32 + i * 16) * 32;
      glds16(Ah_g + (size_t)(m0 + r) * K + k0 + co, &sAh[lb]);
      glds16(Al_g + (size_t)(m0 + r) * K + k0 + co, &sAl[lb]);
      glds16(Bh_g + (size_t)(n0 + r) * ldb + k0 + co, &sBh[lb]);
    }
    __syncthreads();

    bf16x8 ah[4], al[4], bh[4];
#pragma unroll
    for (int mi = 0; mi < 4; ++mi) {
      const int r = wr * 64 + mi * 16 + lr;
      ah[mi] = *reinterpret_cast<const bf16x8*>(&sAh[r * 32 + g * 8]);
      al[mi] = *reinterpret_cast<const bf16x8*>(&sAl[r * 32 + g * 8]);
    }
#pragma unroll
    for (int ni = 0; ni < 4; ++ni) {
      const int r = wc * 64 + ni * 16 + lr;
      bh[ni] = *reinterpret_cast<const bf16x8*>(&sBh[r * 32 + g * 8]);
    }
#pragma unroll
    for (int mi = 0; mi < 4; ++mi)
#pragma unroll
      for (int ni = 0; ni < 4; ++ni) {
        acc[mi][ni] = MFMA(ah[mi], bh[ni], acc[mi][ni]);
        acc[mi][ni] = MFMA(al[mi], bh[ni], acc[mi][ni]);
      }
  }

  const size_t MN = (size_t)M_ROWS * N;
#pragma unroll
  for (int mi = 0; mi < 4; ++mi)
#pragma unroll
    for (int ni = 0; ni < 4; ++ni) {
      const int col = n0 + wc * 64 + ni * 16 + lr;
      const float bv = ((flags & 16) && blockIdx.z == 0) ? bias[col] : 0.f;
#pragma unroll
      for (int r = 0; r < 4; ++r) {
        const int row = m0 + wr * 64 + mi * 16 + g * 4 + r;
        float v = acc[mi][ni][r] + bv;
        if (flags & 1) v = fmaxf(v, 0.f);
        const size_t off = (size_t)row * N + col;
        if (flags & 32) {
          Cf[blockIdx.z * MN + off] = v;
        } else if (flags & 2) {
          atomicAdd(&Cf[off], v);
        } else if (flags & 4) {
          Ch[off] = (bf16)v;
        } else if (flags & 8) {
          bfp sp = fsplit(v);
          Ch[off] = sp.h;
          Cl[off] = sp.l;
        } else {
          Cf[off] = v;
        }
      }
    }
}

// ---------------------------------------------------------------------------
// Flash attention. bf16 in, split-bf16 CTX out.
// Q/K/V element (s,b,h,d) at base[(s*BATCH+b)*stride + h*64 + d].
// Grid (S/128, BATCH*NHEAD), 256 thr. Wave w owns 32 q-rows q0 = qt*128+w*32.
// ---------------------------------------------------------------------------
__launch_bounds__(256)
__global__ void attn_kernel(const bf16* __restrict__ Qg, const bf16* __restrict__ Kg,
                            const bf16* __restrict__ Vg, int qs, int kvs,
                            bf16* __restrict__ Ch, bf16* __restrict__ Cl, int causal) {
  __shared__ bf16 Kl[2][64 * 64];   // swizzled, glds
  __shared__ bf16 Vt[2][64][72];    // [d][key]
  __shared__ bf16 Pl[4][32][68];    // per-wave P relay, stride 68
  const int tid = threadIdx.x, ln = tid & 63, w = tid >> 6;
  const int g = ln >> 4, lr = ln & 15;
  const int qt = blockIdx.x, bh = blockIdx.y;
  const int b = bh >> 4, h = bh & 15;
  const int q0 = qt * 128 + w * 32;

  const int krow8 = ln >> 3, d8 = ln & 7;   // K staging
  const int dq = tid >> 4, kp = tid & 15;   // V staging

  bf16x8 aq[2][2];
#pragma unroll
  for (int mf = 0; mf < 2; ++mf)
#pragma unroll
    for (int kk = 0; kk < 2; ++kk)
      aq[mf][kk] = *reinterpret_cast<const bf16x8*>(
          &Qg[((size_t)(q0 + mf * 16 + lr) * BATCH + b) * qs + h * 64 + kk * 32 + g * 8]);

  f32x4 acco[2][4] = {};
  float mrun[2][4], lrun[2][4];
#pragma unroll
  for (int mf = 0; mf < 2; ++mf)
#pragma unroll
    for (int r = 0; r < 4; ++r) { mrun[mf][r] = -1e30f; lrun[mf][r] = 0.f; }

  const int nkv = causal ? (qt * 2 + 2) : (S_LEN / 64);

  bf16x4 vreg[2][2];
  auto stageK = [&](int kv0, bf16* dst) {
#pragma unroll
    for (int i = 0; i < 2; ++i) {
      const int rbase = i * 32 + w * 8;
      const int row = rbase + krow8;
      glds16(Kg + (size_t)((kv0 + row) * BATCH + b) * kvs + h * 64 + ((d8 ^ (row & 7)) << 3),
             dst + rbase * 64);
    }
  };
  auto loadV = [&](int kv0) {
#pragma unroll
    for (int p = 0; p < 2; ++p) {
      const int k0v = p * 32 + kp * 2;
      vreg[p][0] = *reinterpret_cast<const bf16x4*>(
          &Vg[(size_t)((kv0 + k0v) * BATCH + b) * kvs + h * 64 + dq * 4]);
      vreg[p][1] = *reinterpret_cast<const bf16x4*>(
          &Vg[(size_t)((kv0 + k0v + 1) * BATCH + b) * kvs + h * 64 + dq * 4]);
    }
  };
  auto writeV = [&](int buf) {
#pragma unroll
    for (int p = 0; p < 2; ++p) {
      const int k0v = p * 32 + kp * 2;
#pragma unroll
      for (int i = 0; i < 4; ++i) {
        bf16x2 t2;
        t2[0] = vreg[p][0][i];
        t2[1] = vreg[p][1][i];
        *reinterpret_cast<bf16x2*>(&Vt[buf][dq * 4 + i][k0v]) = t2;
      }
    }
  };

  stageK(0, Kl[0]);
  loadV(0);
  writeV(0);
  __syncthreads();

  for (int kv = 0; kv < nkv; ++kv) {
    const int cur = kv & 1;
    const bool pre = (kv + 1 < nkv);
    if (pre) {  // issue next-tile loads early (T14)
      stageK((kv + 1) * 64, Kl[cur ^ 1]);
      loadV((kv + 1) * 64);
    }
    const int kv0 = kv * 64;

    if (!(causal && kv0 > q0 + 31)) {
      const char* kbase = (const char*)Kl[cur];
      // S = (Q K^T) * 0.125
      f32x4 s[2][4];
      __builtin_amdgcn_s_setprio(1);
#pragma unroll
      for (int mf = 0; mf < 2; ++mf)
#pragma unroll
        for (int c = 0; c < 4; ++c) {
          f32x4 a = {};
#pragma unroll
          for (int kk = 0; kk < 2; ++kk) {
            bf16x8 bk = *reinterpret_cast<const bf16x8*>(
                kbase + (c * 16 + lr) * 128 + ((((kk << 2) + g) ^ (lr & 7)) << 4));
            a = MFMA(aq[mf][kk], bk, a);
          }
          s[mf][c] = a;
        }
      __builtin_amdgcn_s_setprio(0);
#pragma unroll
      for (int mf = 0; mf < 2; ++mf)
#pragma unroll
        for (int c = 0; c < 4; ++c)
#pragma unroll
          for (int r = 0; r < 4; ++r) s[mf][c][r] *= 0.125f;

      if (causal && kv0 + 63 > q0) {
#pragma unroll
        for (int mf = 0; mf < 2; ++mf)
#pragma unroll
          for (int c = 0; c < 4; ++c) {
            const int key = kv0 + c * 16 + lr;
#pragma unroll
            for (int r = 0; r < 4; ++r)
              if (key > q0 + mf * 16 + g * 4 + r) s[mf][c][r] = -1e30f;
          }
      }

      // online softmax: max reduced across 16 lanes; l kept as per-lane partial
#pragma unroll
      for (int mf = 0; mf < 2; ++mf)
#pragma unroll
        for (int r = 0; r < 4; ++r) {
          float mx = fmaxf(fmaxf(s[mf][0][r], s[mf][1][r]), fmaxf(s[mf][2][r], s[mf][3][r]));
#pragma unroll
          for (int off = 8; off >= 1; off >>= 1) mx = fmaxf(mx, __shfl_xor(mx, off));
          const float mnew = fmaxf(mrun[mf][r], mx);
          const float sf = __expf(mrun[mf][r] - mnew);
          float pv[4], ps = 0.f;
#pragma unroll
          for (int c = 0; c < 4; ++c) { pv[c] = __expf(s[mf][c][r] - mnew); ps += pv[c]; }
          lrun[mf][r] = lrun[mf][r] * sf + ps;  // per-lane partial
          mrun[mf][r] = mnew;
#pragma unroll
          for (int t = 0; t < 4; ++t) acco[mf][t][r] *= sf;
#pragma unroll
          for (int c = 0; c < 4; ++c) Pl[w][mf * 16 + g * 4 + r][c * 16 + lr] = (bf16)pv[c];
        }

      // O += P V
      __builtin_amdgcn_s_setprio(1);
#pragma unroll
      for (int mf = 0; mf < 2; ++mf) {
        bf16x8 ap0 = *reinterpret_cast<const bf16x8*>(&Pl[w][mf * 16 + lr][g * 8]);
        bf16x8 ap1 = *reinterpret_cast<const bf16x8*>(&Pl[w][mf * 16 + lr][32 + g * 8]);
#pragma unroll
        for (int t = 0; t < 4; ++t) {
          bf16x8 v0 = *reinterpret_cast<const bf16x8*>(&Vt[cur][t * 16 + lr][g * 8]);
          bf16x8 v1 = *reinterpret_cast<const bf16x8*>(&Vt[cur][t * 16 + lr][32 + g * 8]);
          acco[mf][t] = MFMA(ap0, v0, acco[mf][t]);
          acco[mf][t] = MFMA(ap1, v1, acco[mf][t]);
        }
      }
      __builtin_amdgcn_s_setprio(0);
    }

    if (pre) writeV(cur ^ 1);  // write-late
    __syncthreads();
  }

  // epilogue: finish l reduction, normalize, split-store
#pragma unroll
  for (int mf = 0; mf < 2; ++mf)
#pragma unroll
    for (int r = 0; r < 4; ++r) {
      float l = lrun[mf][r];
#pragma unroll
      for (int off = 8; off >= 1; off >>= 1) l += __shfl_xor(l, off);
      lrun[mf][r] = 1.f / l;
    }
#pragma unroll
  for (int mf = 0; mf < 2; ++mf)
#pragma unroll
    for (int t = 0; t < 4; ++t)
#pragma unroll
      for (int r = 0; r < 4; ++r) {
        const int srow = q0 + mf * 16 + g * 4 + r;
        const size_t off = (size_t)(srow * BATCH + b) * D_MODEL + h * 64 + t * 16 + lr;
        const float v = acco[mf][t][r] * lrun[mf][r];
        bfp sp = fsplit(v);
        Ch[off] = sp.h;
        Cl[off] = sp.l;
      }
}

// ---------------------------------------------------------------------------
// Fused residual add + LayerNorm. O = LN(X + Y0 [+ Y1]); optional split out.
// ---------------------------------------------------------------------------
__launch_bounds__(256)
__global__ void add_ln(const float* __restrict__ X, const float* __restrict__ Y0,
                       const float* __restrict__ Y1,
                       const float* __restrict__ gam, const float* __restrict__ bet,
                       float* __restrict__ O, bf16* __restrict__ Oh, bf16* __restrict__ Ol) {
  const int row = blockIdx.x, tid = threadIdx.x;
  const int lane = tid & 63, w = tid >> 6;
  __shared__ float red[4];
  float4 x = *reinterpret_cast<const float4*>(&X[(size_t)row * D_MODEL + tid * 4]);
  float4 y = *reinterpret_cast<const float4*>(&Y0[(size_t)row * D_MODEL + tid * 4]);
  float v0 = x.x + y.x, v1 = x.y + y.y, v2 = x.z + y.z, v3 = x.w + y.w;
  if (Y1) {
    float4 z = *reinterpret_cast<const float4*>(&Y1[(size_t)row * D_MODEL + tid * 4]);
    v0 += z.x; v1 += z.y; v2 += z.z; v3 += z.w;
  }
  float sm = v0 + v1 + v2 + v3;
#pragma unroll
  for (int off = 32; off >= 1; off >>= 1) sm += __shfl_xor(sm, off);
  if (lane == 0) red[w] = sm;
  __syncthreads();
  float mu = (red[0] + red[1] + red[2] + red[3]) * (1.f / D_MODEL);
  float d0 = v0 - mu, d1 = v1 - mu, d2 = v2 - mu, d3 = v3 - mu;
  float qs = d0 * d0 + d1 * d1 + d2 * d2 + d3 * d3;
#pragma unroll
  for (int off = 32; off >= 1; off >>= 1) qs += __shfl_xor(qs, off);
  __syncthreads();
  if (lane == 0) red[w] = qs;
  __syncthreads();
  float var = (red[0] + red[1] + red[2] + red[3]) * (1.f / D_MODEL);
  float rs = rsqrtf(var + 1e-5f);
  float4 gv = *reinterpret_cast<const float4*>(&gam[tid * 4]);
  float4 bv = *reinterpret_cast<const float4*>(&bet[tid * 4]);
  float4 o;
  o.x = d0 * rs * gv.x + bv.x;
  o.y = d1 * rs * gv.y + bv.y;
  o.z = d2 * rs * gv.z + bv.z;
  o.w = d3 * rs * gv.w + bv.w;
  *reinterpret_cast<float4*>(&O[(size_t)row * D_MODEL + tid * 4]) = o;
  if (Oh) {
    bf16x4 h4, l4;
    bfp s0 = fsplit(o.x); h4[0] = s0.h; l4[0] = s0.l;
    bfp s1 = fsplit(o.y); h4[1] = s1.h; l4[1] = s1.l;
    bfp s2 = fsplit(o.z); h4[2] = s2.h; l4[2] = s2.l;
    bfp s3 = fsplit(o.w); h4[3] = s3.h; l4[3] = s3.l;
    *reinterpret_cast<bf16x4*>(&Oh[(size_t)row * D_MODEL + tid * 4]) = h4;
    *reinterpret_cast<bf16x4*>(&Ol[(size_t)row * D_MODEL + tid * 4]) = l4;
  }
}

// ---------------------------------------------------------------------------
extern "C" void kernel_launch(void* const* d_in, const int* in_sizes, int n_in,
                              void* d_out, int out_size, void* d_ws, size_t ws_size,
                              hipStream_t stream) {
  (void)in_sizes; (void)n_in; (void)out_size; (void)ws_size;
  const float* tgt   = (const float*)d_in[0];
  const float* mem   = (const float*)d_in[1];
  const float* sa_wq = (const float*)d_in[2];
  const float* sa_bq = (const float*)d_in[3];
  const float* sa_wk = (const float*)d_in[4];
  const float* sa_bk = (const float*)d_in[5];
  const float* sa_wv = (const float*)d_in[6];
  const float* sa_bv = (const float*)d_in[7];
  const float* sa_wo = (const float*)d_in[8];
  const float* sa_bo = (const float*)d_in[9];
  const float* ca_wq = (const float*)d_in[10];
  const float* ca_bq = (const float*)d_in[11];
  const float* ca_wk = (const float*)d_in[12];
  const float* ca_bk = (const float*)d_in[13];
  const float* ca_wv = (const float*)d_in[14];
  const float* ca_bv = (const float*)d_in[15];
  const float* ca_wo = (const float*)d_in[16];
  const float* ca_bo = (const float*)d_in[17];
  const float* ff_w1 = (const float*)d_in[18];
  const float* ff_b1 = (const float*)d_in[19];
  const float* ff_w2 = (const float*)d_in[20];
  const float* ff_b2 = (const float*)d_in[21];
  const float* ln1g  = (const float*)d_in[22];
  const float* ln1b  = (const float*)d_in[23];
  const float* ln2g  = (const float*)d_in[24];
  const float* ln2b  = (const float*)d_in[25];
  const float* ln3g  = (const float*)d_in[26];
  const float* ln3b  = (const float*)d_in[27];
  float* out = (float*)d_out;

  char* base = (char*)d_ws;
  const size_t MB = 1u << 20;
  auto B16 = [&](size_t mb) { return (bf16*)(base + mb * MB); };
  auto F32 = [&](size_t mb) { return (float*)(base + mb * MB); };

  // weights (bf16, [N][K] transposed): 0-32 MB
  bf16 *qkvW_h  = B16(0);
  bf16 *sawo_h  = B16(6);
  bf16 *caqW_h  = B16(8);
  bf16 *cakvW_h = B16(10);
  bf16 *cawo_h  = B16(14);
  bf16 *w1_h    = B16(16);
  bf16 *w2_h    = B16(24);
  float* qkv_bias  = F32(32);
  float* cakv_bias = (float*)(base + 32 * MB + 65536);
  // activations
  bf16 *tgt_h = B16(33), *tgt_l = B16(41);    // later X2_hl
  bf16 *mem_h = B16(49), *mem_l = B16(57);
  bf16 *QKV   = B16(65);                      // [4096][3072] (SA)
  bf16 *Qb    = B16(65);                      // CA: [4096][1024]
  bf16 *KVb   = B16(73);                      // CA: [4096][2048]
  bf16 *HC_h  = B16(65), *HC_l = B16(81);     // FFN chunk [4096][2048] (after CA)
  bf16 *CTX_h = B16(89), *CTX_l = B16(97);    // also X1_hl (sequenced)
  float* X1f  = F32(105);
  float* ACC  = F32(121);                     // + z=1 partial at 137
  float* ACC2 = F32(137);
  float* X2f  = F32(153);

  dim3 cb(32, 8);
  auto cast_w = [&](const float* W, int K, int N, bf16* th) {
    hipLaunchKernelGGL(wcast_t, dim3(K / 32, N / 32), cb, 0, stream, W, th, K, N);
  };
  cast_w(sa_wq, 1024, 1024, qkvW_h);
  cast_w(sa_wk, 1024, 1024, qkvW_h + (size_t)1024 * 1024);
  cast_w(sa_wv, 1024, 1024, qkvW_h + (size_t)2048 * 1024);
  cast_w(sa_wo, 1024, 1024, sawo_h);
  cast_w(ca_wq, 1024, 1024, caqW_h);
  cast_w(ca_wk, 1024, 1024, cakvW_h);
  cast_w(ca_wv, 1024, 1024, cakvW_h + (size_t)1024 * 1024);
  cast_w(ca_wo, 1024, 1024, cawo_h);
  cast_w(ff_w1, 1024, 4096, w1_h);
  cast_w(ff_w2, 4096, 1024, w2_h);
  hipMemcpyAsync(qkv_bias,        sa_bq, 4096, hipMemcpyDeviceToDevice, stream);
  hipMemcpyAsync(qkv_bias + 1024, sa_bk, 4096, hipMemcpyDeviceToDevice, stream);
  hipMemcpyAsync(qkv_bias + 2048, sa_bv, 4096, hipMemcpyDeviceToDevice, stream);
  hipMemcpyAsync(cakv_bias,        ca_bk, 4096, hipMemcpyDeviceToDevice, stream);
  hipMemcpyAsync(cakv_bias + 1024, ca_bv, 4096, hipMemcpyDeviceToDevice, stream);
  hipLaunchKernelGGL(act_split, dim3(4096), dim3(256), 0, stream, tgt, tgt_h, tgt_l);
  hipLaunchKernelGGL(act_split, dim3(4096), dim3(256), 0, stream, mem, mem_h, mem_l);

  auto gemm = [&](const bf16* ah, const bf16* al, const bf16* bh,
                  const float* bias, float* cf, bf16* ch, bf16* cl,
                  int N, int K, int ldb, int flags, int Z) {
    hipLaunchKernelGGL(gemm_split, dim3(N / 128, 32, Z), dim3(256), 0, stream,
                       ah, al, bh, bias, cf, ch, cl, N, K, ldb, flags);
  };
  const size_t FBYTES = (size_t)M_ROWS * D_MODEL * 4;

  // ---- self-attention ----
  gemm(tgt_h, tgt_l, qkvW_h, qkv_bias, nullptr, QKV, nullptr, 3072, 1024, 1024, 4 | 16, 1);
  hipLaunchKernelGGL(attn_kernel, dim3(S_LEN / 128, 32), dim3(256), 0, stream,
                     QKV, QKV + 1024, QKV + 2048, 3072, 3072, CTX_h, CTX_l, 1);
  gemm(CTX_h, CTX_l, sawo_h, sa_bo, ACC, nullptr, nullptr, 1024, 1024, 1024, 32 | 16, 2);
  hipLaunchKernelGGL(add_ln, dim3(M_ROWS), dim3(256), 0, stream,
                     tgt, ACC, ACC2, ln1g, ln1b, X1f, CTX_h, CTX_l);

  // ---- cross-attention ----
  gemm(CTX_h, CTX_l, caqW_h, ca_bq, nullptr, Qb, nullptr, 1024, 1024, 1024, 4 | 16, 1);
  gemm(mem_h, mem_l, cakvW_h, cakv_bias, nullptr, KVb, nullptr, 2048, 1024, 1024, 4 | 16, 1);
  hipLaunchKernelGGL(attn_kernel, dim3(S_LEN / 128, 32), dim3(256), 0, stream,
                     Qb, KVb, KVb + 1024, 1024, 2048, CTX_h, CTX_l, 0);
  gemm(CTX_h, CTX_l, cawo_h, ca_bo, ACC, nullptr, nullptr, 1024, 1024, 1024, 32 | 16, 2);
  hipLaunchKernelGGL(add_ln, dim3(M_ROWS), dim3(256), 0, stream,
                     X1f, ACC, ACC2, ln2g, ln2b, X2f, tgt_h, tgt_l);

  // ---- FFN: 2 chunks of D_FF=2048; W2 K-split z=2, atomic accumulate ----
  hipMemsetAsync(ACC, 0, FBYTES, stream);
  for (int c = 0; c < 2; ++c) {
    gemm(tgt_h, tgt_l, w1_h + (size_t)c * 2048 * 1024, ff_b1 + c * 2048,
         nullptr, HC_h, HC_l, 2048, 1024, 1024, 8 | 16 | 1, 1);
    gemm(HC_h, HC_l, w2_h + c * 2048, ff_b2, ACC, nullptr, nullptr,
         1024, 2048, 4096, 2 | (c == 0 ? 16 : 0), 2);
  }
  hipLaunchKernelGGL(add_ln, dim3(M_ROWS), dim3(256), 0, stream,
                     X2f, ACC, nullptr, ln3g, ln3b, out, nullptr, nullptr);
}